// Round 4
// baseline (167.166 us; speedup 1.0000x reference)
//
#include <hip/hip_runtime.h>
#include <hip/hip_bf16.h>

#define NROWS 2048

typedef float f32x4 __attribute__((ext_vector_type(4)));
typedef __bf16 bf16x8 __attribute__((ext_vector_type(8)));
typedef short s16x8 __attribute__((ext_vector_type(8)));

typedef const __attribute__((address_space(1))) unsigned int* gas_t;
typedef __attribute__((address_space(3))) unsigned int* las_t;

__device__ __forceinline__ unsigned short f2bf(float f) {
    unsigned int u = __float_as_uint(f);
    unsigned int r = (u + 0x7FFFu + ((u >> 16) & 1u)) >> 16;
    return (unsigned short)r;
}
__device__ __forceinline__ float bf2f(unsigned short u) {
    return __uint_as_float((unsigned int)u << 16);
}
__device__ __forceinline__ f32x4 mfma16(s16x8 a, s16x8 b, f32x4 c) {
    return __builtin_amdgcn_mfma_f32_16x16x32_bf16(
        __builtin_bit_cast(bf16x8, a), __builtin_bit_cast(bf16x8, b), c, 0, 0, 0);
}

// ---------------- gather x ----------------
__global__ void k_gather_x(const float* __restrict__ lhs, const int* __restrict__ idx,
                           unsigned short* __restrict__ xb) {
    int tid = blockIdx.x * 256 + threadIdx.x;
    int n = tid >> 8;
    int c = (tid & 255) << 2;
    int b = n >> 8, k = n & 255;
    int srow = idx[(b << 8) + k];
    const float4 v = *reinterpret_cast<const float4*>(
        lhs + (((size_t)b << 9) + srow) * 1024 + c);
    ushort4 o = make_ushort4(f2bf(v.x), f2bf(v.y), f2bf(v.z), f2bf(v.w));
    *reinterpret_cast<ushort4*>(xb + (size_t)n * 1024 + c) = o;
}

// ---------------- fused weight conversion ----------------
__global__ void k_convert_all(const float* __restrict__ hw, const float* __restrict__ p0w,
                              const float* __restrict__ p1w, const float* __restrict__ o0w,
                              const float* __restrict__ o1w,
                              unsigned short* __restrict__ hWb, unsigned short* __restrict__ pW01,
                              unsigned short* __restrict__ o0Wb, unsigned short* __restrict__ o1Wb) {
    const long B0 = 2048L * 1024;
    const long B1 = B0 + 384L * 1024;
    const long B2 = B1 + 8064L * 256;
    const long B3 = B2 + 40320L * 64;
    long e = ((long)blockIdx.x * 256 + threadIdx.x) * 4;
    if (e >= B3) return;
    const float* src; unsigned short* dst; long rows; int colshift; long base;
    if (e < B0)      { base = 0;  src = hw;  dst = hWb;  rows = 2002;  colshift = 10; }
    else if (e < B1) {
        long l = e - B0;
        long row = l >> 10;
        unsigned short* d = pW01 + l;
        ushort4 o;
        if (row < 256) {
            float4 v = *reinterpret_cast<const float4*>(p0w + l);
            o = make_ushort4(f2bf(v.x), f2bf(v.y), f2bf(v.z), f2bf(v.w));
        } else if (row < 320) {
            float4 v = *reinterpret_cast<const float4*>(p1w + (l - 256L * 1024));
            o = make_ushort4(f2bf(v.x), f2bf(v.y), f2bf(v.z), f2bf(v.w));
        } else {
            o = make_ushort4(0, 0, 0, 0);
        }
        *reinterpret_cast<ushort4*>(d) = o;
        return;
    }
    else if (e < B2) { base = B1; src = o0w; dst = o0Wb; rows = 8000;  colshift = 8; }
    else             { base = B2; src = o1w; dst = o1Wb; rows = 40257; colshift = 6; }
    long l = e - base;
    long row = l >> colshift;
    ushort4 o;
    if (row < rows) {
        float4 v = *reinterpret_cast<const float4*>(src + l);
        o = make_ushort4(f2bf(v.x), f2bf(v.y), f2bf(v.z), f2bf(v.w));
    } else {
        o = make_ushort4(0, 0, 0, 0);
    }
    *reinterpret_cast<ushort4*>(dst + l) = o;
}

// ---------------- prep: padded bias + clipped target cols ----------------
__global__ void k_prep(const float* __restrict__ hb, const int* __restrict__ tgt,
                       float* __restrict__ bias_pad, int* __restrict__ tc) {
    int n = blockIdx.x * 256 + threadIdx.x;
    if (n >= 2048) return;
    bias_pad[n] = (n < 2002) ? hb[n] : -1e30f;
    int t = tgt[n];
    tc[n] = min(t, 1999);
    tc[2048 + n] = min(max(t - 2000, 0), 7999);
    tc[4096 + n] = min(max(t - 10000, 0), 40256);
}

// ---------------- 128x128-tile GEMM, BK=64, depth-3 counted-vmcnt pipeline ------
// Blocks with blockIdx.y <  fsplit: fused exp-sum epilogue (per-64-col strip
//   partial[strip][row], optional bias).
// Blocks with blockIdx.y >= fsplit: store bf16 hout[row][c], c = col - fsplit*128.
template <int NT>
__global__ __launch_bounds__(256)
void k_mm(const unsigned short* __restrict__ A, int lda,
          const unsigned short* __restrict__ B, int ldb,
          const float* __restrict__ bias, float* __restrict__ partial,
          unsigned short* __restrict__ hout, int hstride, int hcols, int fsplit) {
    __shared__ unsigned short As[3][128 * 64];
    __shared__ unsigned short Bs[3][128 * 64];
    const int tid = threadIdx.x;
    const int lane = tid & 63, wid = tid >> 6;
    const int wr = wid >> 1, wc = wid & 1;
    const int g = lane >> 4, cl = lane & 15;
    const int row0 = blockIdx.x * 128;
    const int col0 = blockIdx.y * 128;

    const int sr = wid * 8 + (lane >> 3);     // staging row 0..31 per issue group
    const int skc = (lane & 7) * 8;           // staging k-col (elems)
    const unsigned short* Ab = A + (size_t)row0 * lda + skc;
    const unsigned short* Bb = B + (size_t)col0 * ldb + skc;

    auto stage = [&](int buf, int kt) {
        const unsigned short* ga = Ab + (size_t)sr * lda + kt;
        const unsigned short* gb = Bb + (size_t)sr * ldb + kt;
        unsigned short* la = &As[buf][wid * 8 * 64];
        unsigned short* lb = &Bs[buf][wid * 8 * 64];
#pragma unroll
        for (int i = 0; i < 4; ++i) {
            __builtin_amdgcn_global_load_lds((gas_t)(const void*)(ga + (size_t)i * 32 * lda),
                                             (las_t)(void*)(la + i * 32 * 64), 16, 0, 0);
            __builtin_amdgcn_global_load_lds((gas_t)(const void*)(gb + (size_t)i * 32 * ldb),
                                             (las_t)(void*)(lb + i * 32 * 64), 16, 0, 0);
        }
    };

    f32x4 acc[4][4] = {};
    stage(0, 0);
    stage(1, 64);
    for (int t = 0; t < NT; ++t) {
        if (t == NT - 1) {
            asm volatile("s_waitcnt vmcnt(0)" ::: "memory");
        } else {
            asm volatile("s_waitcnt vmcnt(8)" ::: "memory");   // stage t landed; t+1 in flight
        }
        __builtin_amdgcn_s_barrier();
        if (t + 2 < NT) stage((t + 2) % 3, (t + 2) * 64);
        const unsigned short* Al = &As[t % 3][(wr * 64 + cl) * 64 + g * 8];
        const unsigned short* Bl = &Bs[t % 3][(wc * 64 + cl) * 64 + g * 8];
#pragma unroll
        for (int kk = 0; kk < 64; kk += 32) {
            s16x8 a[4], b[4];
#pragma unroll
            for (int mi = 0; mi < 4; ++mi)
                a[mi] = *reinterpret_cast<const s16x8*>(Al + mi * 16 * 64 + kk);
#pragma unroll
            for (int ni = 0; ni < 4; ++ni)
                b[ni] = *reinterpret_cast<const s16x8*>(Bl + ni * 16 * 64 + kk);
#pragma unroll
            for (int mi = 0; mi < 4; ++mi)
#pragma unroll
                for (int ni = 0; ni < 4; ++ni)
                    acc[mi][ni] = mfma16(a[mi], b[ni], acc[mi][ni]);
        }
        if (t + 1 < NT) __builtin_amdgcn_s_barrier();  // protect buf reuse ordering
    }

    if ((int)blockIdx.y >= fsplit) {
        int c0 = col0 - fsplit * 128;
#pragma unroll
        for (int mi = 0; mi < 4; ++mi)
#pragma unroll
            for (int ni = 0; ni < 4; ++ni) {
                int col = c0 + wc * 64 + ni * 16 + cl;
                if (col < hcols) {
#pragma unroll
                    for (int r = 0; r < 4; ++r) {
                        int row = row0 + wr * 64 + mi * 16 + g * 4 + r;
                        hout[(size_t)row * hstride + col] = f2bf(acc[mi][ni][r]);
                    }
                }
            }
    } else {
        float bv[4];
#pragma unroll
        for (int ni = 0; ni < 4; ++ni)
            bv[ni] = bias ? bias[col0 + wc * 64 + ni * 16 + cl] : 0.f;
        int strip = blockIdx.y * 2 + wc;
#pragma unroll
        for (int mi = 0; mi < 4; ++mi)
#pragma unroll
            for (int r = 0; r < 4; ++r) {
                float s = 0.f;
#pragma unroll
                for (int ni = 0; ni < 4; ++ni)
                    s += __expf(acc[mi][ni][r] + bv[ni]);
                s += __shfl_xor(s, 1, 64);
                s += __shfl_xor(s, 2, 64);
                s += __shfl_xor(s, 4, 64);
                s += __shfl_xor(s, 8, 64);
                if (cl == 0)
                    partial[(size_t)strip * NROWS + row0 + wr * 64 + mi * 16 + g * 4 + r] = s;
            }
    }
}

// ---------------- out1 panel GEMM (K=64, A+B in regs, B double-buffered) ----------
// Each block: 128 rows x 3 column tiles of 128. exp-sums accumulated across all
// 3 tiles; one reduce at the end -> p1[(blockIdx.y*2+wc)][row].
__global__ __launch_bounds__(256)
void k_out1(const unsigned short* __restrict__ h01, const unsigned short* __restrict__ B,
            float* __restrict__ p1) {
    const int lane = threadIdx.x & 63, wid = threadIdx.x >> 6;
    const int wr = wid >> 1, wc = wid & 1;
    const int g = lane >> 4, cl = lane & 15;
    const int row0 = blockIdx.x * 128 + wr * 64;
    const int tile0 = blockIdx.y * 3;

    s16x8 a[4][2];
#pragma unroll
    for (int mi = 0; mi < 4; ++mi)
#pragma unroll
        for (int kk = 0; kk < 2; ++kk)
            a[mi][kk] = *reinterpret_cast<const s16x8*>(
                h01 + (size_t)(row0 + mi * 16 + cl) * 320 + 256 + kk * 32 + g * 8);

    auto loadB = [&](s16x8 (&b)[4][2], int tile) {
        int colb = tile * 128 + wc * 64;
#pragma unroll
        for (int ni = 0; ni < 4; ++ni)
#pragma unroll
            for (int kk = 0; kk < 2; ++kk)
                b[ni][kk] = *reinterpret_cast<const s16x8*>(
                    B + (size_t)(colb + ni * 16 + cl) * 64 + kk * 32 + g * 8);
    };

    float sexp[4][4] = {};
    const f32x4 z4 = {0.f, 0.f, 0.f, 0.f};
    auto compute = [&](s16x8 (&b)[4][2]) {
        f32x4 acc[4][4];
#pragma unroll
        for (int mi = 0; mi < 4; ++mi)
#pragma unroll
            for (int ni = 0; ni < 4; ++ni)
                acc[mi][ni] = mfma16(a[mi][0], b[ni][0], z4);
#pragma unroll
        for (int mi = 0; mi < 4; ++mi)
#pragma unroll
            for (int ni = 0; ni < 4; ++ni)
                acc[mi][ni] = mfma16(a[mi][1], b[ni][1], acc[mi][ni]);
#pragma unroll
        for (int mi = 0; mi < 4; ++mi)
#pragma unroll
            for (int ni = 0; ni < 4; ++ni)
#pragma unroll
                for (int r = 0; r < 4; ++r)
                    sexp[mi][r] += __expf(acc[mi][ni][r]);
    };

    s16x8 bA[4][2], bB[4][2];
    loadB(bA, tile0);
    loadB(bB, tile0 + 1);
    compute(bA);               // tile 0 (tile 1 loads in flight)
    loadB(bA, tile0 + 2);      // prefetch tile 2 under tile-1 compute
    compute(bB);               // tile 1
    compute(bA);               // tile 2

#pragma unroll
    for (int mi = 0; mi < 4; ++mi)
#pragma unroll
        for (int r = 0; r < 4; ++r) {
            float s = sexp[mi][r];
            s += __shfl_xor(s, 1, 64);
            s += __shfl_xor(s, 2, 64);
            s += __shfl_xor(s, 4, 64);
            s += __shfl_xor(s, 8, 64);
            if (cl == 0)
                p1[(size_t)(blockIdx.y * 2 + wc) * NROWS + row0 + mi * 16 + g * 4 + r] = s;
        }
}

// ---------------- per-row target / routing dots ----------------
__global__ __launch_bounds__(256)
void k_dots(const unsigned short* __restrict__ xb, const unsigned short* __restrict__ h01,
            const float* __restrict__ headW, const float* __restrict__ bias_pad,
            const float* __restrict__ o0w, const float* __restrict__ o1w,
            const int* __restrict__ tc,
            float* __restrict__ tgh, float* __restrict__ r0, float* __restrict__ r1,
            float* __restrict__ tg0, float* __restrict__ tg1) {
    int lane = threadIdx.x & 63;
    int n = (blockIdx.x * 256 + threadIdx.x) >> 6;
    int tch = tc[n], tc0 = tc[2048 + n], tc1 = tc[4096 + n];
    const unsigned short* xr = xb + (size_t)n * 1024 + lane * 16;
    s16x8 x0 = *reinterpret_cast<const s16x8*>(xr);
    s16x8 x1 = *reinterpret_cast<const s16x8*>(xr + 8);
    const float* wh = headW + (size_t)tch * 1024 + lane * 16;
    const float* wa = headW + (size_t)2000 * 1024 + lane * 16;
    const float* wb = headW + (size_t)2001 * 1024 + lane * 16;
    float dh = 0.f, da = 0.f, db = 0.f;
#pragma unroll
    for (int i = 0; i < 8; ++i) {
        float xv = bf2f((unsigned short)x0[i]);
        dh += xv * wh[i]; da += xv * wa[i]; db += xv * wb[i];
    }
#pragma unroll
    for (int i = 0; i < 8; ++i) {
        float xv = bf2f((unsigned short)x1[i]);
        dh += xv * wh[8 + i]; da += xv * wa[8 + i]; db += xv * wb[8 + i];
    }
    ushort4 h0v = *reinterpret_cast<const ushort4*>(h01 + (size_t)n * 320 + lane * 4);
    float4 w0v = *reinterpret_cast<const float4*>(o0w + (size_t)tc0 * 256 + lane * 4);
    float d2 = bf2f(h0v.x) * w0v.x + bf2f(h0v.y) * w0v.y +
               bf2f(h0v.z) * w0v.z + bf2f(h0v.w) * w0v.w;
    float d3 = bf2f(h01[(size_t)n * 320 + 256 + lane]) * o1w[(size_t)tc1 * 64 + lane];
#pragma unroll
    for (int m = 1; m < 64; m <<= 1) {
        dh += __shfl_xor(dh, m, 64);
        da += __shfl_xor(da, m, 64);
        db += __shfl_xor(db, m, 64);
        d2 += __shfl_xor(d2, m, 64);
        d3 += __shfl_xor(d3, m, 64);
    }
    if (lane == 0) {
        tgh[n] = dh + bias_pad[tch];
        r0[n] = da + bias_pad[2000];
        r1[n] = db + bias_pad[2001];
        tg0[n] = d2;
        tg1[n] = d3;
    }
}

// ---------------- finalize ----------------
__global__ void k_finalize(const float* __restrict__ ph, const float* __restrict__ p0,
                           const float* __restrict__ p1, const float* __restrict__ tgh,
                           const float* __restrict__ r0, const float* __restrict__ r1,
                           const float* __restrict__ tg0, const float* __restrict__ tg1,
                           const int* __restrict__ tgt, float* __restrict__ outv,
                           float* __restrict__ bsum) {
    int n = blockIdx.x * 128 + threadIdx.x;   // 16 blocks x 128
    float sh = 0.f, s0 = 0.f, s1 = 0.f;
    for (int s = 0; s < 32; ++s) sh += ph[(size_t)s * NROWS + n];
    for (int s = 0; s < 126; ++s) s0 += p0[(size_t)s * NROWS + n];
    for (int s = 0; s < 210; ++s) s1 += p1[(size_t)s * NROWS + n];
    s0 -= 64.f;   // zero-weight pad cols contribute exp(0)=1 each
    s1 -= 63.f;
    float lh = __logf(sh), l0 = __logf(s0), l1 = __logf(s1);
    int t = tgt[n];
    float o;
    if (t < 2000) o = tgh[n] - lh;
    else if (t < 10000) o = (r0[n] - lh) + (tg0[n] - l0);
    else o = (r1[n] - lh) + (tg1[n] - l1);
    outv[n] = o;
    __shared__ float red[128];
    red[threadIdx.x] = o;
    __syncthreads();
    for (int s = 64; s > 0; s >>= 1) {
        if (threadIdx.x < s) red[threadIdx.x] += red[threadIdx.x + s];
        __syncthreads();
    }
    if (threadIdx.x == 0) bsum[blockIdx.x] = red[0];
}

__global__ void k_loss(const float* __restrict__ bsum, float* __restrict__ loss) {
    float s = 0.f;
    for (int i = 0; i < 16; ++i) s += bsum[i];
    *loss = -s / (float)NROWS;
}

extern "C" void kernel_launch(void* const* d_in, const int* in_sizes, int n_in,
                              void* d_out, int out_size, void* d_ws, size_t ws_size,
                              hipStream_t stream) {
    const int* targets   = (const int*)d_in[0];
    const float* lhs     = (const float*)d_in[1];
    const int* idx       = (const int*)d_in[3];
    const float* head_W  = (const float*)d_in[4];
    const float* head_b  = (const float*)d_in[5];
    const float* proj0_W = (const float*)d_in[6];
    const float* out0_W  = (const float*)d_in[7];
    const float* proj1_W = (const float*)d_in[8];
    const float* out1_W  = (const float*)d_in[9];

    char* ws = (char*)d_ws;
    size_t off = 0;
    auto alloc = [&](size_t bytes) -> void* {
        void* p = ws + off;
        off += (bytes + 255) & ~(size_t)255;
        return p;
    };

    unsigned short* xb   = (unsigned short*)alloc((size_t)2048 * 1024 * 2);
    // head weights (2048 rows) + proj weights (384 rows) CONTIGUOUS: B' = 2432 x 1024
    unsigned short* wB   = (unsigned short*)alloc((size_t)2432 * 1024 * 2);
    unsigned short* hWb  = wB;
    unsigned short* pW01 = wB + (size_t)2048 * 1024;
    unsigned short* o0Wb = (unsigned short*)alloc((size_t)8064 * 256 * 2);
    unsigned short* o1Wb = (unsigned short*)alloc((size_t)40320 * 64 * 2);
    unsigned short* h01  = (unsigned short*)alloc((size_t)2048 * 320 * 2);
    float* ph  = (float*)alloc((size_t)32 * 2048 * 4);
    float* p0  = (float*)alloc((size_t)126 * 2048 * 4);
    float* p1  = (float*)alloc((size_t)210 * 2048 * 4);
    float* tgh = (float*)alloc(2048 * 4);
    float* r0  = (float*)alloc(2048 * 4);
    float* r1  = (float*)alloc(2048 * 4);
    float* tg0 = (float*)alloc(2048 * 4);
    float* tg1 = (float*)alloc(2048 * 4);
    int*   tc  = (int*)alloc(3 * 2048 * 4);
    float* bias_pad = (float*)alloc(2048 * 4);
    float* bsum = (float*)alloc(16 * 4);

    k_gather_x<<<2048, 256, 0, stream>>>(lhs, idx, xb);
    k_convert_all<<<6968, 256, 0, stream>>>(head_W, proj0_W, proj1_W, out0_W, out1_W,
                                            hWb, pW01, o0Wb, o1Wb);
    k_prep<<<8, 256, 0, stream>>>(head_b, targets, bias_pad, tc);

    // head (y<16: fused exp-sum, 32 strips) + proj (y>=16: store h01) in ONE launch
    k_mm<16><<<dim3(16, 19), 256, 0, stream>>>(
        xb, 1024, wB, 1024, bias_pad, ph, h01, 320, 320, 16);
    // out0: 2048 x 8064, K=256, fused exp-sum (126 strips)
    k_mm<4><<<dim3(16, 63), 256, 0, stream>>>(
        h01, 320, o0Wb, 256, nullptr, p0, nullptr, 0, 0, 63);
    // out1: 2048 x 40320, K=64, fused exp-sum (210 strips)
    k_out1<<<dim3(16, 105), 256, 0, stream>>>(h01, o1Wb, p1);

    k_dots<<<512, 256, 0, stream>>>(xb, h01, head_W, bias_pad, out0_W, out1_W, tc,
                                    tgh, r0, r1, tg0, tg1);

    float* outv = (float*)d_out;
    float* loss = (float*)d_out + NROWS;
    k_finalize<<<16, 128, 0, stream>>>(ph, p0, p1, tgh, r0, r1, tg0, tg1, targets, outv, bsum);
    k_loss<<<1, 1, 0, stream>>>(bsum, loss);
}

// Round 5
// 141.138 us; speedup vs baseline: 1.1844x; 1.1844x over previous
//
#include <hip/hip_runtime.h>
#include <hip/hip_bf16.h>

#define NROWS 2048
#define L2E 1.4426950408889634f

typedef float f32x4 __attribute__((ext_vector_type(4)));
typedef __bf16 bf16x8 __attribute__((ext_vector_type(8)));
typedef short s16x8 __attribute__((ext_vector_type(8)));

typedef const __attribute__((address_space(1))) unsigned int* gas_t;
typedef __attribute__((address_space(3))) unsigned int* las_t;

__device__ __forceinline__ unsigned short f2bf(float f) {
    unsigned int u = __float_as_uint(f);
    unsigned int r = (u + 0x7FFFu + ((u >> 16) & 1u)) >> 16;
    return (unsigned short)r;
}
__device__ __forceinline__ float bf2f(unsigned short u) {
    return __uint_as_float((unsigned int)u << 16);
}
__device__ __forceinline__ f32x4 mfma16(s16x8 a, s16x8 b, f32x4 c) {
    return __builtin_amdgcn_mfma_f32_16x16x32_bf16(
        __builtin_bit_cast(bf16x8, a), __builtin_bit_cast(bf16x8, b), c, 0, 0, 0);
}

// ---------------- gather x ----------------
__global__ void k_gather_x(const float* __restrict__ lhs, const int* __restrict__ idx,
                           unsigned short* __restrict__ xb) {
    int tid = blockIdx.x * 256 + threadIdx.x;
    int n = tid >> 8;
    int c = (tid & 255) << 2;
    int b = n >> 8, k = n & 255;
    int srow = idx[(b << 8) + k];
    const float4 v = *reinterpret_cast<const float4*>(
        lhs + (((size_t)b << 9) + srow) * 1024 + c);
    ushort4 o = make_ushort4(f2bf(v.x), f2bf(v.y), f2bf(v.z), f2bf(v.w));
    *reinterpret_cast<ushort4*>(xb + (size_t)n * 1024 + c) = o;
}

// ---------------- fused weight conversion (exp-sum weights pre-scaled by log2e) ---
__global__ void k_convert_all(const float* __restrict__ hw, const float* __restrict__ p0w,
                              const float* __restrict__ p1w, const float* __restrict__ o0w,
                              const float* __restrict__ o1w,
                              unsigned short* __restrict__ hWb, unsigned short* __restrict__ pW01,
                              unsigned short* __restrict__ o0Wb, unsigned short* __restrict__ o1Wb) {
    const long B0 = 2048L * 1024;
    const long B1 = B0 + 384L * 1024;
    const long B2 = B1 + 8064L * 256;
    const long B3 = B2 + 40320L * 64;
    long e = ((long)blockIdx.x * 256 + threadIdx.x) * 4;
    if (e >= B3) return;
    const float* src; unsigned short* dst; long rows; int colshift; long base;
    float sc;
    if (e < B0)      { base = 0;  src = hw;  dst = hWb;  rows = 2002;  colshift = 10; sc = L2E; }
    else if (e < B1) {
        long l = e - B0;
        long row = l >> 10;
        unsigned short* d = pW01 + l;
        ushort4 o;
        if (row < 256) {
            float4 v = *reinterpret_cast<const float4*>(p0w + l);
            o = make_ushort4(f2bf(v.x), f2bf(v.y), f2bf(v.z), f2bf(v.w));
        } else if (row < 320) {
            float4 v = *reinterpret_cast<const float4*>(p1w + (l - 256L * 1024));
            o = make_ushort4(f2bf(v.x), f2bf(v.y), f2bf(v.z), f2bf(v.w));
        } else {
            o = make_ushort4(0, 0, 0, 0);
        }
        *reinterpret_cast<ushort4*>(d) = o;
        return;
    }
    else if (e < B2) { base = B1; src = o0w; dst = o0Wb; rows = 8000;  colshift = 8; sc = L2E; }
    else             { base = B2; src = o1w; dst = o1Wb; rows = 40257; colshift = 6; sc = L2E; }
    long l = e - base;
    long row = l >> colshift;
    ushort4 o;
    if (row < rows) {
        float4 v = *reinterpret_cast<const float4*>(src + l);
        o = make_ushort4(f2bf(v.x * sc), f2bf(v.y * sc), f2bf(v.z * sc), f2bf(v.w * sc));
    } else {
        o = make_ushort4(0, 0, 0, 0);
    }
    *reinterpret_cast<ushort4*>(dst + l) = o;
}

// ---------------- prep: log2e-scaled padded bias + clipped target cols ----------
__global__ void k_prep(const float* __restrict__ hb, const int* __restrict__ tgt,
                       float* __restrict__ bias_s, int* __restrict__ tc) {
    int n = blockIdx.x * 256 + threadIdx.x;
    if (n >= 2048) return;
    bias_s[n] = (n < 2002) ? hb[n] * L2E : -1e30f;
    int t = tgt[n];
    tc[n] = min(t, 1999);
    tc[2048 + n] = min(max(t - 2000, 0), 7999);
    tc[4096 + n] = min(max(t - 10000, 0), 40256);
}

// ---------------- 128x128-tile GEMM, BK=64, depth-3 counted-vmcnt pipeline ------
// blockIdx.y < fsplit: fused exp2-sum epilogue (B pre-scaled by log2e).
// blockIdx.y >= fsplit: store bf16 hout[row][c], c = col - fsplit*128.
template <int NT>
__global__ __launch_bounds__(256)
void k_mm(const unsigned short* __restrict__ A, int lda,
          const unsigned short* __restrict__ B, int ldb,
          const float* __restrict__ bias, float* __restrict__ partial,
          unsigned short* __restrict__ hout, int hstride, int hcols, int fsplit) {
    __shared__ unsigned short As[3][128 * 64];
    __shared__ unsigned short Bs[3][128 * 64];
    const int tid = threadIdx.x;
    const int lane = tid & 63, wid = tid >> 6;
    const int wr = wid >> 1, wc = wid & 1;
    const int g = lane >> 4, cl = lane & 15;
    const int row0 = blockIdx.x * 128;
    const int col0 = blockIdx.y * 128;

    const int sr = wid * 8 + (lane >> 3);     // staging row 0..31 per issue group
    const int skc = (lane & 7) * 8;           // staging k-col (elems)
    const unsigned short* Ab = A + (size_t)row0 * lda + skc;
    const unsigned short* Bb = B + (size_t)col0 * ldb + skc;

    auto stage = [&](int buf, int kt) {
        const unsigned short* ga = Ab + (size_t)sr * lda + kt;
        const unsigned short* gb = Bb + (size_t)sr * ldb + kt;
        unsigned short* la = &As[buf][wid * 8 * 64];
        unsigned short* lb = &Bs[buf][wid * 8 * 64];
#pragma unroll
        for (int i = 0; i < 4; ++i) {
            __builtin_amdgcn_global_load_lds((gas_t)(const void*)(ga + (size_t)i * 32 * lda),
                                             (las_t)(void*)(la + i * 32 * 64), 16, 0, 0);
            __builtin_amdgcn_global_load_lds((gas_t)(const void*)(gb + (size_t)i * 32 * ldb),
                                             (las_t)(void*)(lb + i * 32 * 64), 16, 0, 0);
        }
    };

    f32x4 acc[4][4] = {};
    stage(0, 0);
    stage(1, 64);
    for (int t = 0; t < NT; ++t) {
        if (t == NT - 1) {
            asm volatile("s_waitcnt vmcnt(0)" ::: "memory");
        } else {
            asm volatile("s_waitcnt vmcnt(8)" ::: "memory");   // stage t landed; t+1 in flight
        }
        __builtin_amdgcn_s_barrier();
        if (t + 2 < NT) stage((t + 2) % 3, (t + 2) * 64);
        const unsigned short* Al = &As[t % 3][(wr * 64 + cl) * 64 + g * 8];
        const unsigned short* Bl = &Bs[t % 3][(wc * 64 + cl) * 64 + g * 8];
#pragma unroll
        for (int kk = 0; kk < 64; kk += 32) {
            s16x8 a[4], b[4];
#pragma unroll
            for (int mi = 0; mi < 4; ++mi)
                a[mi] = *reinterpret_cast<const s16x8*>(Al + mi * 16 * 64 + kk);
#pragma unroll
            for (int ni = 0; ni < 4; ++ni)
                b[ni] = *reinterpret_cast<const s16x8*>(Bl + ni * 16 * 64 + kk);
#pragma unroll
            for (int mi = 0; mi < 4; ++mi)
#pragma unroll
                for (int ni = 0; ni < 4; ++ni)
                    acc[mi][ni] = mfma16(a[mi], b[ni], acc[mi][ni]);
        }
    }

    if ((int)blockIdx.y >= fsplit) {
        int c0 = col0 - fsplit * 128;
#pragma unroll
        for (int mi = 0; mi < 4; ++mi)
#pragma unroll
            for (int ni = 0; ni < 4; ++ni) {
                int col = c0 + wc * 64 + ni * 16 + cl;
                if (col < hcols) {
#pragma unroll
                    for (int r = 0; r < 4; ++r) {
                        int row = row0 + wr * 64 + mi * 16 + g * 4 + r;
                        hout[(size_t)row * hstride + col] = f2bf(acc[mi][ni][r]);
                    }
                }
            }
    } else {
        float bv[4];
#pragma unroll
        for (int ni = 0; ni < 4; ++ni)
            bv[ni] = bias ? bias[col0 + wc * 64 + ni * 16 + cl] : 0.f;
        int strip = blockIdx.y * 2 + wc;
#pragma unroll
        for (int mi = 0; mi < 4; ++mi)
#pragma unroll
            for (int r = 0; r < 4; ++r) {
                float s = 0.f;
#pragma unroll
                for (int ni = 0; ni < 4; ++ni)
                    s += __builtin_amdgcn_exp2f(acc[mi][ni][r] + bv[ni]);
                s += __shfl_xor(s, 1, 64);
                s += __shfl_xor(s, 2, 64);
                s += __shfl_xor(s, 4, 64);
                s += __shfl_xor(s, 8, 64);
                if (cl == 0)
                    partial[(size_t)strip * NROWS + row0 + wr * 64 + mi * 16 + g * 4 + r] = s;
            }
    }
}

// ---------------- out1: K=64 A in regs, B through LDS, 7 col-tiles per block ------
// LDS staged with T2 XOR-swizzle (pre-swizzled global source, linear LDS dest).
#define OUT1_NT 7
__global__ __launch_bounds__(256)
void k_out1(const unsigned short* __restrict__ h01, const unsigned short* __restrict__ B,
            float* __restrict__ p1) {
    __shared__ unsigned short Bs[3][128 * 64];
    const int tid = threadIdx.x;
    const int lane = tid & 63, wid = tid >> 6;
    const int wr = wid >> 1, wc = wid & 1;
    const int g = lane >> 4, cl = lane & 15;
    const int row0 = blockIdx.x * 128 + wr * 64;
    const int t0 = blockIdx.y * OUT1_NT;

    // A fragments (K=64) in registers for the whole block lifetime
    s16x8 a[4][2];
#pragma unroll
    for (int mi = 0; mi < 4; ++mi)
#pragma unroll
        for (int kk = 0; kk < 2; ++kk)
            a[mi][kk] = *reinterpret_cast<const s16x8*>(
                h01 + (size_t)(row0 + mi * 16 + cl) * 320 + 256 + kk * 32 + g * 8);

    const int sr = wid * 8 + (lane >> 3);                  // 0..31: B row within tile
    const int swz = ((lane & 7) ^ (lane >> 3)) * 8;        // pre-swizzled k-slot (elems)
    auto stage = [&](int buf, int tile) {
        const unsigned short* gb = B + ((size_t)tile * 128 + sr) * 64 + swz;
        unsigned short* lb = &Bs[buf][wid * 8 * 64];
#pragma unroll
        for (int i = 0; i < 4; ++i)
            __builtin_amdgcn_global_load_lds((gas_t)(const void*)(gb + (size_t)i * 32 * 64),
                                             (las_t)(void*)(lb + i * 32 * 64), 16, 0, 0);
    };

    float sexp[4][4] = {};
    const f32x4 z4 = {0.f, 0.f, 0.f, 0.f};

    stage(0, t0);
    stage(1, t0 + 1);
    for (int it = 0; it < OUT1_NT; ++it) {
        if (it == OUT1_NT - 1) {
            asm volatile("s_waitcnt vmcnt(0)" ::: "memory");
        } else {
            asm volatile("s_waitcnt vmcnt(4)" ::: "memory");   // tile it landed; it+1 in flight
        }
        __builtin_amdgcn_s_barrier();
        if (it + 2 < OUT1_NT) stage((it + 2) % 3, t0 + it + 2);
        const unsigned short* Bl = Bs[it % 3];
        s16x8 b[4][2];
#pragma unroll
        for (int ni = 0; ni < 4; ++ni) {
            int colrow = wc * 64 + ni * 16 + cl;
#pragma unroll
            for (int kkidx = 0; kkidx < 2; ++kkidx) {
                int slot = (kkidx * 4 + g) ^ (cl & 7);     // read-side un-swizzle
                b[ni][kkidx] = *reinterpret_cast<const s16x8*>(Bl + colrow * 64 + slot * 8);
            }
        }
#pragma unroll
        for (int ni = 0; ni < 4; ++ni) {
            f32x4 acc[4];
#pragma unroll
            for (int mi = 0; mi < 4; ++mi)
                acc[mi] = mfma16(a[mi][0], b[ni][0], z4);
#pragma unroll
            for (int mi = 0; mi < 4; ++mi)
                acc[mi] = mfma16(a[mi][1], b[ni][1], acc[mi]);
#pragma unroll
            for (int mi = 0; mi < 4; ++mi)
#pragma unroll
                for (int r = 0; r < 4; ++r)
                    sexp[mi][r] += __builtin_amdgcn_exp2f(acc[mi][r]);
        }
    }

#pragma unroll
    for (int mi = 0; mi < 4; ++mi)
#pragma unroll
        for (int r = 0; r < 4; ++r) {
            float s = sexp[mi][r];
            s += __shfl_xor(s, 1, 64);
            s += __shfl_xor(s, 2, 64);
            s += __shfl_xor(s, 4, 64);
            s += __shfl_xor(s, 8, 64);
            if (cl == 0)
                p1[(size_t)(blockIdx.y * 2 + wc) * NROWS + row0 + mi * 16 + g * 4 + r] = s;
        }
}

// ---------------- per-row target / routing dots ----------------
__global__ __launch_bounds__(256)
void k_dots(const unsigned short* __restrict__ xb, const unsigned short* __restrict__ h01,
            const float* __restrict__ headW, const float* __restrict__ hb,
            const float* __restrict__ o0w, const float* __restrict__ o1w,
            const int* __restrict__ tc,
            float* __restrict__ tgh, float* __restrict__ r0, float* __restrict__ r1,
            float* __restrict__ tg0, float* __restrict__ tg1) {
    int lane = threadIdx.x & 63;
    int n = (blockIdx.x * 256 + threadIdx.x) >> 6;
    int tch = tc[n], tc0 = tc[2048 + n], tc1 = tc[4096 + n];
    const unsigned short* xr = xb + (size_t)n * 1024 + lane * 16;
    s16x8 x0 = *reinterpret_cast<const s16x8*>(xr);
    s16x8 x1 = *reinterpret_cast<const s16x8*>(xr + 8);
    const float* wh = headW + (size_t)tch * 1024 + lane * 16;
    const float* wa = headW + (size_t)2000 * 1024 + lane * 16;
    const float* wb = headW + (size_t)2001 * 1024 + lane * 16;
    float dh = 0.f, da = 0.f, db = 0.f;
#pragma unroll
    for (int i = 0; i < 8; ++i) {
        float xv = bf2f((unsigned short)x0[i]);
        dh += xv * wh[i]; da += xv * wa[i]; db += xv * wb[i];
    }
#pragma unroll
    for (int i = 0; i < 8; ++i) {
        float xv = bf2f((unsigned short)x1[i]);
        dh += xv * wh[8 + i]; da += xv * wa[8 + i]; db += xv * wb[8 + i];
    }
    ushort4 h0v = *reinterpret_cast<const ushort4*>(h01 + (size_t)n * 320 + lane * 4);
    float4 w0v = *reinterpret_cast<const float4*>(o0w + (size_t)tc0 * 256 + lane * 4);
    float d2 = bf2f(h0v.x) * w0v.x + bf2f(h0v.y) * w0v.y +
               bf2f(h0v.z) * w0v.z + bf2f(h0v.w) * w0v.w;
    float d3 = bf2f(h01[(size_t)n * 320 + 256 + lane]) * o1w[(size_t)tc1 * 64 + lane];
#pragma unroll
    for (int m = 1; m < 64; m <<= 1) {
        dh += __shfl_xor(dh, m, 64);
        da += __shfl_xor(da, m, 64);
        db += __shfl_xor(db, m, 64);
        d2 += __shfl_xor(d2, m, 64);
        d3 += __shfl_xor(d3, m, 64);
    }
    if (lane == 0) {
        tgh[n] = dh + hb[tch];
        r0[n] = da + hb[2000];
        r1[n] = db + hb[2001];
        tg0[n] = d2;
        tg1[n] = d3;
    }
}

// ---------------- finalize ----------------
__global__ void k_finalize(const float* __restrict__ ph, const float* __restrict__ p0,
                           const float* __restrict__ p1, const float* __restrict__ tgh,
                           const float* __restrict__ r0, const float* __restrict__ r1,
                           const float* __restrict__ tg0, const float* __restrict__ tg1,
                           const int* __restrict__ tgt, float* __restrict__ outv,
                           float* __restrict__ bsum) {
    int n = blockIdx.x * 128 + threadIdx.x;   // 16 blocks x 128
    float sh = 0.f, s0 = 0.f, s1 = 0.f;
    for (int s = 0; s < 32; ++s) sh += ph[(size_t)s * NROWS + n];
    for (int s = 0; s < 126; ++s) s0 += p0[(size_t)s * NROWS + n];
    for (int s = 0; s < 90; ++s) s1 += p1[(size_t)s * NROWS + n];
    s0 -= 64.f;   // zero-weight pad cols contribute exp2(0)=1 each
    s1 -= 63.f;
    float lh = __logf(sh), l0 = __logf(s0), l1 = __logf(s1);
    int t = tgt[n];
    float o;
    if (t < 2000) o = tgh[n] - lh;
    else if (t < 10000) o = (r0[n] - lh) + (tg0[n] - l0);
    else o = (r1[n] - lh) + (tg1[n] - l1);
    outv[n] = o;
    __shared__ float red[128];
    red[threadIdx.x] = o;
    __syncthreads();
    for (int s = 64; s > 0; s >>= 1) {
        if (threadIdx.x < s) red[threadIdx.x] += red[threadIdx.x + s];
        __syncthreads();
    }
    if (threadIdx.x == 0) bsum[blockIdx.x] = red[0];
}

__global__ void k_loss(const float* __restrict__ bsum, float* __restrict__ loss) {
    float s = 0.f;
    for (int i = 0; i < 16; ++i) s += bsum[i];
    *loss = -s / (float)NROWS;
}

extern "C" void kernel_launch(void* const* d_in, const int* in_sizes, int n_in,
                              void* d_out, int out_size, void* d_ws, size_t ws_size,
                              hipStream_t stream) {
    const int* targets   = (const int*)d_in[0];
    const float* lhs     = (const float*)d_in[1];
    const int* idx       = (const int*)d_in[3];
    const float* head_W  = (const float*)d_in[4];
    const float* head_b  = (const float*)d_in[5];
    const float* proj0_W = (const float*)d_in[6];
    const float* out0_W  = (const float*)d_in[7];
    const float* proj1_W = (const float*)d_in[8];
    const float* out1_W  = (const float*)d_in[9];

    char* ws = (char*)d_ws;
    size_t off = 0;
    auto alloc = [&](size_t bytes) -> void* {
        void* p = ws + off;
        off += (bytes + 255) & ~(size_t)255;
        return p;
    };

    unsigned short* xb   = (unsigned short*)alloc((size_t)2048 * 1024 * 2);
    // head weights (2048 rows, log2e-scaled) + proj weights (384 rows, raw): B' = 2432 x 1024
    unsigned short* wB   = (unsigned short*)alloc((size_t)2432 * 1024 * 2);
    unsigned short* hWb  = wB;
    unsigned short* pW01 = wB + (size_t)2048 * 1024;
    unsigned short* o0Wb = (unsigned short*)alloc((size_t)8064 * 256 * 2);
    unsigned short* o1Wb = (unsigned short*)alloc((size_t)40320 * 64 * 2);
    unsigned short* h01  = (unsigned short*)alloc((size_t)2048 * 320 * 2);
    float* ph  = (float*)alloc((size_t)32 * 2048 * 4);
    float* p0  = (float*)alloc((size_t)126 * 2048 * 4);
    float* p1  = (float*)alloc((size_t)90 * 2048 * 4);
    float* tgh = (float*)alloc(2048 * 4);
    float* r0  = (float*)alloc(2048 * 4);
    float* r1  = (float*)alloc(2048 * 4);
    float* tg0 = (float*)alloc(2048 * 4);
    float* tg1 = (float*)alloc(2048 * 4);
    int*   tc  = (int*)alloc(3 * 2048 * 4);
    float* bias_s = (float*)alloc(2048 * 4);
    float* bsum = (float*)alloc(16 * 4);

    k_gather_x<<<2048, 256, 0, stream>>>(lhs, idx, xb);
    k_convert_all<<<6968, 256, 0, stream>>>(head_W, proj0_W, proj1_W, out0_W, out1_W,
                                            hWb, pW01, o0Wb, o1Wb);
    k_prep<<<8, 256, 0, stream>>>(head_b, targets, bias_s, tc);

    // head (y<16: fused exp2-sum, 32 strips) + proj (y>=16: store h01) in ONE launch
    k_mm<16><<<dim3(16, 19), 256, 0, stream>>>(
        xb, 1024, wB, 1024, bias_s, ph, h01, 320, 320, 16);
    // out0: 2048 x 8064, K=256, fused exp2-sum (126 strips)
    k_mm<4><<<dim3(16, 63), 256, 0, stream>>>(
        h01, 320, o0Wb, 256, nullptr, p0, nullptr, 0, 0, 63);
    // out1: 2048 x 40320, K=64, fused exp2-sum (90 strips)
    k_out1<<<dim3(16, 45), 256, 0, stream>>>(h01, o1Wb, p1);

    k_dots<<<512, 256, 0, stream>>>(xb, h01, head_W, head_b, out0_W, out1_W, tc,
                                    tgh, r0, r1, tg0, tg1);

    float* outv = (float*)d_out;
    float* loss = (float*)d_out + NROWS;
    k_finalize<<<16, 128, 0, stream>>>(ph, p0, p1, tgh, r0, r1, tg0, tg1, targets, outv, bsum);
    k_loss<<<1, 1, 0, stream>>>(bsum, loss);
}

// Round 6
// 110.702 us; speedup vs baseline: 1.5101x; 1.2749x over previous
//
#include <hip/hip_runtime.h>
#include <hip/hip_bf16.h>

#define NROWS 2048
#define L2E 1.4426950408889634f

typedef float f32x4 __attribute__((ext_vector_type(4)));
typedef __bf16 bf16x8 __attribute__((ext_vector_type(8)));
typedef short s16x8 __attribute__((ext_vector_type(8)));

typedef const __attribute__((address_space(1))) unsigned int* gas_t;
typedef __attribute__((address_space(3))) unsigned int* las_t;

__device__ __forceinline__ unsigned short f2bf(float f) {
    unsigned int u = __float_as_uint(f);
    unsigned int r = (u + 0x7FFFu + ((u >> 16) & 1u)) >> 16;
    return (unsigned short)r;
}
__device__ __forceinline__ float bf2f(unsigned short u) {
    return __uint_as_float((unsigned int)u << 16);
}
__device__ __forceinline__ f32x4 mfma16(s16x8 a, s16x8 b, f32x4 c) {
    return __builtin_amdgcn_mfma_f32_16x16x32_bf16(
        __builtin_bit_cast(bf16x8, a), __builtin_bit_cast(bf16x8, b), c, 0, 0, 0);
}

// ---------------- gather x ----------------
__global__ void k_gather_x(const float* __restrict__ lhs, const int* __restrict__ idx,
                           unsigned short* __restrict__ xb) {
    int tid = blockIdx.x * 256 + threadIdx.x;
    int n = tid >> 8;
    int c = (tid & 255) << 2;
    int b = n >> 8, k = n & 255;
    int srow = idx[(b << 8) + k];
    const float4 v = *reinterpret_cast<const float4*>(
        lhs + (((size_t)b << 9) + srow) * 1024 + c);
    ushort4 o = make_ushort4(f2bf(v.x), f2bf(v.y), f2bf(v.z), f2bf(v.w));
    *reinterpret_cast<ushort4*>(xb + (size_t)n * 1024 + c) = o;
}

// ---------------- fused weight conversion (exp-sum weights pre-scaled by log2e) ---
__global__ void k_convert_all(const float* __restrict__ hw, const float* __restrict__ p0w,
                              const float* __restrict__ p1w, const float* __restrict__ o0w,
                              const float* __restrict__ o1w,
                              unsigned short* __restrict__ hWb, unsigned short* __restrict__ pW01,
                              unsigned short* __restrict__ o0Wb, unsigned short* __restrict__ o1Wb) {
    const long B0 = 2048L * 1024;
    const long B1 = B0 + 384L * 1024;
    const long B2 = B1 + 8064L * 256;
    const long B3 = B2 + 40320L * 64;
    long e = ((long)blockIdx.x * 256 + threadIdx.x) * 4;
    if (e >= B3) return;
    const float* src; unsigned short* dst; long rows; int colshift; long base;
    float sc;
    if (e < B0)      { base = 0;  src = hw;  dst = hWb;  rows = 2002;  colshift = 10; sc = L2E; }
    else if (e < B1) {
        long l = e - B0;
        long row = l >> 10;
        unsigned short* d = pW01 + l;
        ushort4 o;
        if (row < 256) {
            float4 v = *reinterpret_cast<const float4*>(p0w + l);
            o = make_ushort4(f2bf(v.x), f2bf(v.y), f2bf(v.z), f2bf(v.w));
        } else if (row < 320) {
            float4 v = *reinterpret_cast<const float4*>(p1w + (l - 256L * 1024));
            o = make_ushort4(f2bf(v.x), f2bf(v.y), f2bf(v.z), f2bf(v.w));
        } else {
            o = make_ushort4(0, 0, 0, 0);
        }
        *reinterpret_cast<ushort4*>(d) = o;
        return;
    }
    else if (e < B2) { base = B1; src = o0w; dst = o0Wb; rows = 8000;  colshift = 8; sc = L2E; }
    else             { base = B2; src = o1w; dst = o1Wb; rows = 40257; colshift = 6; sc = L2E; }
    long l = e - base;
    long row = l >> colshift;
    ushort4 o;
    if (row < rows) {
        float4 v = *reinterpret_cast<const float4*>(src + l);
        o = make_ushort4(f2bf(v.x * sc), f2bf(v.y * sc), f2bf(v.z * sc), f2bf(v.w * sc));
    } else {
        o = make_ushort4(0, 0, 0, 0);
    }
    *reinterpret_cast<ushort4*>(dst + l) = o;
}

// ---------------- prep: log2e-scaled padded bias + clipped target cols ----------
__global__ void k_prep(const float* __restrict__ hb, const int* __restrict__ tgt,
                       float* __restrict__ bias_s, int* __restrict__ tc) {
    int n = blockIdx.x * 256 + threadIdx.x;
    if (n >= 2048) return;
    bias_s[n] = (n < 2002) ? hb[n] * L2E : -1e30f;
    int t = tgt[n];
    tc[n] = min(t, 1999);
    tc[2048 + n] = min(max(t - 2000, 0), 7999);
    tc[4096 + n] = min(max(t - 10000, 0), 40256);
}

// ---------------- 128x128-tile GEMM, BK=64, T3-minimum dbuf + T2 XOR swizzle ------
// 2 LDS stages (64KB -> 2 blocks/CU). One vmcnt(0)+barrier per K-step.
// LDS tiles XOR-swizzled: 16B slot s of row r holds global slot s^(r&7)
// (pre-swizzled global source, linear LDS dest; read applies same XOR).
// blockIdx.y < fsplit: fused exp2-sum epilogue (B pre-scaled by log2e).
// blockIdx.y >= fsplit: store bf16 hout[row][c], c = col - fsplit*128.
template <int NT>
__global__ __launch_bounds__(256)
void k_mm(const unsigned short* __restrict__ A, int lda,
          const unsigned short* __restrict__ B, int ldb,
          const float* __restrict__ bias, float* __restrict__ partial,
          unsigned short* __restrict__ hout, int hstride, int hcols, int fsplit) {
    __shared__ unsigned short As[2][128 * 64];
    __shared__ unsigned short Bs[2][128 * 64];
    const int tid = threadIdx.x;
    const int lane = tid & 63, wid = tid >> 6;
    const int wr = wid >> 1, wc = wid & 1;
    const int g = lane >> 4, cl = lane & 15;
    const int row0 = blockIdx.x * 128;
    const int col0 = blockIdx.y * 128;

    const int sr = wid * 8 + (lane >> 3);                  // staging row 0..31 (+i*32)
    const int swz = ((lane & 7) ^ (lane >> 3)) * 8;        // pre-swizzled k-slot (elems)
    const unsigned short* Ab = A + (size_t)(row0 + sr) * lda + swz;
    const unsigned short* Bb = B + (size_t)(col0 + sr) * ldb + swz;

    auto stage = [&](int buf, int kt) {
        const unsigned short* ga = Ab + kt;
        const unsigned short* gb = Bb + kt;
        unsigned short* la = &As[buf][wid * 8 * 64];
        unsigned short* lb = &Bs[buf][wid * 8 * 64];
#pragma unroll
        for (int i = 0; i < 4; ++i) {
            __builtin_amdgcn_global_load_lds((gas_t)(const void*)(ga + (size_t)i * 32 * lda),
                                             (las_t)(void*)(la + i * 32 * 64), 16, 0, 0);
            __builtin_amdgcn_global_load_lds((gas_t)(const void*)(gb + (size_t)i * 32 * ldb),
                                             (las_t)(void*)(lb + i * 32 * 64), 16, 0, 0);
        }
    };

    f32x4 acc[4][4] = {};
    stage(0, 0);
    asm volatile("s_waitcnt vmcnt(0)" ::: "memory");
    __builtin_amdgcn_s_barrier();
    const int sA = (cl & 7);                               // read-side XOR (row&7 == cl&7)
    for (int t = 0; t < NT; ++t) {
        if (t + 1 < NT) stage((t + 1) & 1, (t + 1) * 64);
        const unsigned short* Al = &As[t & 1][(wr * 64 + cl) * 64];
        const unsigned short* Bl = &Bs[t & 1][(wc * 64 + cl) * 64];
#pragma unroll
        for (int kk2 = 0; kk2 < 2; ++kk2) {
            const int slot = ((kk2 * 4 + g) ^ sA) * 8;
            s16x8 a[4], b[4];
#pragma unroll
            for (int mi = 0; mi < 4; ++mi)
                a[mi] = *reinterpret_cast<const s16x8*>(Al + mi * 16 * 64 + slot);
#pragma unroll
            for (int ni = 0; ni < 4; ++ni)
                b[ni] = *reinterpret_cast<const s16x8*>(Bl + ni * 16 * 64 + slot);
#pragma unroll
            for (int mi = 0; mi < 4; ++mi)
#pragma unroll
                for (int ni = 0; ni < 4; ++ni)
                    acc[mi][ni] = mfma16(a[mi], b[ni], acc[mi][ni]);
        }
        if (t + 1 < NT) {
            asm volatile("s_waitcnt vmcnt(0)" ::: "memory");
            __builtin_amdgcn_s_barrier();
        }
    }

    if ((int)blockIdx.y >= fsplit) {
        int c0 = col0 - fsplit * 128;
#pragma unroll
        for (int mi = 0; mi < 4; ++mi)
#pragma unroll
            for (int ni = 0; ni < 4; ++ni) {
                int col = c0 + wc * 64 + ni * 16 + cl;
                if (col < hcols) {
#pragma unroll
                    for (int r = 0; r < 4; ++r) {
                        int row = row0 + wr * 64 + mi * 16 + g * 4 + r;
                        hout[(size_t)row * hstride + col] = f2bf(acc[mi][ni][r]);
                    }
                }
            }
    } else {
        float bv[4];
#pragma unroll
        for (int ni = 0; ni < 4; ++ni)
            bv[ni] = bias ? bias[col0 + wc * 64 + ni * 16 + cl] : 0.f;
        int strip = blockIdx.y * 2 + wc;
#pragma unroll
        for (int mi = 0; mi < 4; ++mi)
#pragma unroll
            for (int r = 0; r < 4; ++r) {
                float s = 0.f;
#pragma unroll
                for (int ni = 0; ni < 4; ++ni)
                    s += __builtin_amdgcn_exp2f(acc[mi][ni][r] + bv[ni]);
                s += __shfl_xor(s, 1, 64);
                s += __shfl_xor(s, 2, 64);
                s += __shfl_xor(s, 4, 64);
                s += __shfl_xor(s, 8, 64);
                if (cl == 0)
                    partial[(size_t)strip * NROWS + row0 + wr * 64 + mi * 16 + g * 4 + r] = s;
            }
    }
}

// ---------------- out1: K=64 A in regs, B through LDS, 7 col-tiles per block ------
// LDS staged with T2 XOR-swizzle (pre-swizzled global source, linear LDS dest).
#define OUT1_NT 7
__global__ __launch_bounds__(256)
void k_out1(const unsigned short* __restrict__ h01, const unsigned short* __restrict__ B,
            float* __restrict__ p1) {
    __shared__ unsigned short Bs[3][128 * 64];
    const int tid = threadIdx.x;
    const int lane = tid & 63, wid = tid >> 6;
    const int wr = wid >> 1, wc = wid & 1;
    const int g = lane >> 4, cl = lane & 15;
    const int row0 = blockIdx.x * 128 + wr * 64;
    const int t0 = blockIdx.y * OUT1_NT;

    // A fragments (K=64) in registers for the whole block lifetime
    s16x8 a[4][2];
#pragma unroll
    for (int mi = 0; mi < 4; ++mi)
#pragma unroll
        for (int kk = 0; kk < 2; ++kk)
            a[mi][kk] = *reinterpret_cast<const s16x8*>(
                h01 + (size_t)(row0 + mi * 16 + cl) * 320 + 256 + kk * 32 + g * 8);

    const int sr = wid * 8 + (lane >> 3);                  // 0..31: B row within tile
    const int swz = ((lane & 7) ^ (lane >> 3)) * 8;        // pre-swizzled k-slot (elems)
    auto stage = [&](int buf, int tile) {
        const unsigned short* gb = B + ((size_t)tile * 128 + sr) * 64 + swz;
        unsigned short* lb = &Bs[buf][wid * 8 * 64];
#pragma unroll
        for (int i = 0; i < 4; ++i)
            __builtin_amdgcn_global_load_lds((gas_t)(const void*)(gb + (size_t)i * 32 * 64),
                                             (las_t)(void*)(lb + i * 32 * 64), 16, 0, 0);
    };

    float sexp[4][4] = {};
    const f32x4 z4 = {0.f, 0.f, 0.f, 0.f};

    stage(0, t0);
    stage(1, t0 + 1);
    for (int it = 0; it < OUT1_NT; ++it) {
        if (it == OUT1_NT - 1) {
            asm volatile("s_waitcnt vmcnt(0)" ::: "memory");
        } else {
            asm volatile("s_waitcnt vmcnt(4)" ::: "memory");   // tile it landed; it+1 in flight
        }
        __builtin_amdgcn_s_barrier();
        if (it + 2 < OUT1_NT) stage((it + 2) % 3, t0 + it + 2);
        const unsigned short* Bl = Bs[it % 3];
        s16x8 b[4][2];
#pragma unroll
        for (int ni = 0; ni < 4; ++ni) {
            int colrow = wc * 64 + ni * 16 + cl;
#pragma unroll
            for (int kkidx = 0; kkidx < 2; ++kkidx) {
                int slot = (kkidx * 4 + g) ^ (cl & 7);     // read-side un-swizzle
                b[ni][kkidx] = *reinterpret_cast<const s16x8*>(Bl + colrow * 64 + slot * 8);
            }
        }
#pragma unroll
        for (int ni = 0; ni < 4; ++ni) {
            f32x4 acc[4];
#pragma unroll
            for (int mi = 0; mi < 4; ++mi)
                acc[mi] = mfma16(a[mi][0], b[ni][0], z4);
#pragma unroll
            for (int mi = 0; mi < 4; ++mi)
                acc[mi] = mfma16(a[mi][1], b[ni][1], acc[mi]);
#pragma unroll
            for (int mi = 0; mi < 4; ++mi)
#pragma unroll
                for (int r = 0; r < 4; ++r)
                    sexp[mi][r] += __builtin_amdgcn_exp2f(acc[mi][r]);
        }
    }

#pragma unroll
    for (int mi = 0; mi < 4; ++mi)
#pragma unroll
        for (int r = 0; r < 4; ++r) {
            float s = sexp[mi][r];
            s += __shfl_xor(s, 1, 64);
            s += __shfl_xor(s, 2, 64);
            s += __shfl_xor(s, 4, 64);
            s += __shfl_xor(s, 8, 64);
            if (cl == 0)
                p1[(size_t)(blockIdx.y * 2 + wc) * NROWS + row0 + mi * 16 + g * 4 + r] = s;
        }
}

// ---------------- per-row target / routing dots ----------------
__global__ __launch_bounds__(256)
void k_dots(const unsigned short* __restrict__ xb, const unsigned short* __restrict__ h01,
            const float* __restrict__ headW, const float* __restrict__ hb,
            const float* __restrict__ o0w, const float* __restrict__ o1w,
            const int* __restrict__ tc,
            float* __restrict__ tgh, float* __restrict__ r0, float* __restrict__ r1,
            float* __restrict__ tg0, float* __restrict__ tg1) {
    int lane = threadIdx.x & 63;
    int n = (blockIdx.x * 256 + threadIdx.x) >> 6;
    int tch = tc[n], tc0 = tc[2048 + n], tc1 = tc[4096 + n];
    const unsigned short* xr = xb + (size_t)n * 1024 + lane * 16;
    s16x8 x0 = *reinterpret_cast<const s16x8*>(xr);
    s16x8 x1 = *reinterpret_cast<const s16x8*>(xr + 8);
    const float* wh = headW + (size_t)tch * 1024 + lane * 16;
    const float* wa = headW + (size_t)2000 * 1024 + lane * 16;
    const float* wb = headW + (size_t)2001 * 1024 + lane * 16;
    float dh = 0.f, da = 0.f, db = 0.f;
#pragma unroll
    for (int i = 0; i < 8; ++i) {
        float xv = bf2f((unsigned short)x0[i]);
        dh += xv * wh[i]; da += xv * wa[i]; db += xv * wb[i];
    }
#pragma unroll
    for (int i = 0; i < 8; ++i) {
        float xv = bf2f((unsigned short)x1[i]);
        dh += xv * wh[8 + i]; da += xv * wa[8 + i]; db += xv * wb[8 + i];
    }
    ushort4 h0v = *reinterpret_cast<const ushort4*>(h01 + (size_t)n * 320 + lane * 4);
    float4 w0v = *reinterpret_cast<const float4*>(o0w + (size_t)tc0 * 256 + lane * 4);
    float d2 = bf2f(h0v.x) * w0v.x + bf2f(h0v.y) * w0v.y +
               bf2f(h0v.z) * w0v.z + bf2f(h0v.w) * w0v.w;
    float d3 = bf2f(h01[(size_t)n * 320 + 256 + lane]) * o1w[(size_t)tc1 * 64 + lane];
#pragma unroll
    for (int m = 1; m < 64; m <<= 1) {
        dh += __shfl_xor(dh, m, 64);
        da += __shfl_xor(da, m, 64);
        db += __shfl_xor(db, m, 64);
        d2 += __shfl_xor(d2, m, 64);
        d3 += __shfl_xor(d3, m, 64);
    }
    if (lane == 0) {
        tgh[n] = dh + hb[tch];
        r0[n] = da + hb[2000];
        r1[n] = db + hb[2001];
        tg0[n] = d2;
        tg1[n] = d3;
    }
}

// ---------------- finalize ----------------
__global__ void k_finalize(const float* __restrict__ ph, const float* __restrict__ p0,
                           const float* __restrict__ p1, const float* __restrict__ tgh,
                           const float* __restrict__ r0, const float* __restrict__ r1,
                           const float* __restrict__ tg0, const float* __restrict__ tg1,
                           const int* __restrict__ tgt, float* __restrict__ outv,
                           float* __restrict__ bsum) {
    int n = blockIdx.x * 128 + threadIdx.x;   // 16 blocks x 128
    float sh = 0.f, s0 = 0.f, s1 = 0.f;
    for (int s = 0; s < 32; ++s) sh += ph[(size_t)s * NROWS + n];
    for (int s = 0; s < 126; ++s) s0 += p0[(size_t)s * NROWS + n];
    for (int s = 0; s < 90; ++s) s1 += p1[(size_t)s * NROWS + n];
    s0 -= 64.f;   // zero-weight pad cols contribute exp2(0)=1 each
    s1 -= 63.f;
    float lh = __logf(sh), l0 = __logf(s0), l1 = __logf(s1);
    int t = tgt[n];
    float o;
    if (t < 2000) o = tgh[n] - lh;
    else if (t < 10000) o = (r0[n] - lh) + (tg0[n] - l0);
    else o = (r1[n] - lh) + (tg1[n] - l1);
    outv[n] = o;
    __shared__ float red[128];
    red[threadIdx.x] = o;
    __syncthreads();
    for (int s = 64; s > 0; s >>= 1) {
        if (threadIdx.x < s) red[threadIdx.x] += red[threadIdx.x + s];
        __syncthreads();
    }
    if (threadIdx.x == 0) bsum[blockIdx.x] = red[0];
}

__global__ void k_loss(const float* __restrict__ bsum, float* __restrict__ loss) {
    float s = 0.f;
    for (int i = 0; i < 16; ++i) s += bsum[i];
    *loss = -s / (float)NROWS;
}

extern "C" void kernel_launch(void* const* d_in, const int* in_sizes, int n_in,
                              void* d_out, int out_size, void* d_ws, size_t ws_size,
                              hipStream_t stream) {
    const int* targets   = (const int*)d_in[0];
    const float* lhs     = (const float*)d_in[1];
    const int* idx       = (const int*)d_in[3];
    const float* head_W  = (const float*)d_in[4];
    const float* head_b  = (const float*)d_in[5];
    const float* proj0_W = (const float*)d_in[6];
    const float* out0_W  = (const float*)d_in[7];
    const float* proj1_W = (const float*)d_in[8];
    const float* out1_W  = (const float*)d_in[9];

    char* ws = (char*)d_ws;
    size_t off = 0;
    auto alloc = [&](size_t bytes) -> void* {
        void* p = ws + off;
        off += (bytes + 255) & ~(size_t)255;
        return p;
    };

    unsigned short* xb   = (unsigned short*)alloc((size_t)2048 * 1024 * 2);
    // head weights (2048 rows, log2e-scaled) + proj weights (384 rows, raw): B' = 2432 x 1024
    unsigned short* wB   = (unsigned short*)alloc((size_t)2432 * 1024 * 2);
    unsigned short* hWb  = wB;
    unsigned short* pW01 = wB + (size_t)2048 * 1024;
    unsigned short* o0Wb = (unsigned short*)alloc((size_t)8064 * 256 * 2);
    unsigned short* o1Wb = (unsigned short*)alloc((size_t)40320 * 64 * 2);
    unsigned short* h01  = (unsigned short*)alloc((size_t)2048 * 320 * 2);
    float* ph  = (float*)alloc((size_t)32 * 2048 * 4);
    float* p0  = (float*)alloc((size_t)126 * 2048 * 4);
    float* p1  = (float*)alloc((size_t)90 * 2048 * 4);
    float* tgh = (float*)alloc(2048 * 4);
    float* r0  = (float*)alloc(2048 * 4);
    float* r1  = (float*)alloc(2048 * 4);
    float* tg0 = (float*)alloc(2048 * 4);
    float* tg1 = (float*)alloc(2048 * 4);
    int*   tc  = (int*)alloc(3 * 2048 * 4);
    float* bias_s = (float*)alloc(2048 * 4);
    float* bsum = (float*)alloc(16 * 4);

    k_gather_x<<<2048, 256, 0, stream>>>(lhs, idx, xb);
    k_convert_all<<<6968, 256, 0, stream>>>(head_W, proj0_W, proj1_W, out0_W, out1_W,
                                            hWb, pW01, o0Wb, o1Wb);
    k_prep<<<8, 256, 0, stream>>>(head_b, targets, bias_s, tc);

    // head (y<16: fused exp2-sum, 32 strips) + proj (y>=16: store h01) in ONE launch
    k_mm<16><<<dim3(16, 19), 256, 0, stream>>>(
        xb, 1024, wB, 1024, bias_s, ph, h01, 320, 320, 16);
    // out0: 2048 x 8064, K=256, fused exp2-sum (126 strips)
    k_mm<4><<<dim3(16, 63), 256, 0, stream>>>(
        h01, 320, o0Wb, 256, nullptr, p0, nullptr, 0, 0, 63);
    // out1: 2048 x 40320, K=64, fused exp2-sum (90 strips)
    k_out1<<<dim3(16, 45), 256, 0, stream>>>(h01, o1Wb, p1);

    k_dots<<<512, 256, 0, stream>>>(xb, h01, head_W, head_b, out0_W, out1_W, tc,
                                    tgh, r0, r1, tg0, tg1);

    float* outv = (float*)d_out;
    float* loss = (float*)d_out + NROWS;
    k_finalize<<<16, 128, 0, stream>>>(ph, p0, p1, tgh, r0, r1, tg0, tg1, targets, outv, bsum);
    k_loss<<<1, 1, 0, stream>>>(bsum, loss);
}

// Round 7
// 92.396 us; speedup vs baseline: 1.8092x; 1.1981x over previous
//
#include <hip/hip_runtime.h>
#include <hip/hip_bf16.h>

#define NROWS 2048
#define L2E 1.4426950408889634f

typedef float f32x4 __attribute__((ext_vector_type(4)));
typedef __bf16 bf16x8 __attribute__((ext_vector_type(8)));
typedef short s16x8 __attribute__((ext_vector_type(8)));

typedef const __attribute__((address_space(1))) unsigned int* gas_t;
typedef __attribute__((address_space(3))) unsigned int* las_t;

__device__ __forceinline__ unsigned short f2bf(float f) {
    unsigned int u = __float_as_uint(f);
    unsigned int r = (u + 0x7FFFu + ((u >> 16) & 1u)) >> 16;
    return (unsigned short)r;
}
__device__ __forceinline__ float bf2f(unsigned short u) {
    return __uint_as_float((unsigned int)u << 16);
}
__device__ __forceinline__ f32x4 mfma16(s16x8 a, s16x8 b, f32x4 c) {
    return __builtin_amdgcn_mfma_f32_16x16x32_bf16(
        __builtin_bit_cast(bf16x8, a), __builtin_bit_cast(bf16x8, b), c, 0, 0, 0);
}

// ---------------- merged prologue: gather x | convert weights | prep ----------------
__global__ void k_prologue(const float* __restrict__ lhs, const int* __restrict__ idx,
                           const float* __restrict__ hw, const float* __restrict__ p0w,
                           const float* __restrict__ p1w, const float* __restrict__ o0w,
                           const float* __restrict__ o1w, const float* __restrict__ hb,
                           const int* __restrict__ tgt,
                           unsigned short* __restrict__ xb, unsigned short* __restrict__ hWb,
                           unsigned short* __restrict__ pW01, unsigned short* __restrict__ o0Wb,
                           unsigned short* __restrict__ o1Wb,
                           float* __restrict__ bias_s, int* __restrict__ tc) {
    int bid = blockIdx.x;
    if (bid < 2048) {                      // ---- gather x: 2048 rows x 1024 cols bf16
        int tid = bid * 256 + threadIdx.x;
        int n = tid >> 8;
        int c = (tid & 255) << 2;
        int b = n >> 8, k = n & 255;
        int srow = idx[(b << 8) + k];
        const float4 v = *reinterpret_cast<const float4*>(
            lhs + (((size_t)b << 9) + srow) * 1024 + c);
        ushort4 o = make_ushort4(f2bf(v.x), f2bf(v.y), f2bf(v.z), f2bf(v.w));
        *reinterpret_cast<ushort4*>(xb + (size_t)n * 1024 + c) = o;
        return;
    }
    bid -= 2048;
    if (bid < 6968) {                      // ---- weight conversion (exp-weights * log2e)
        const long B0 = 2048L * 1024;
        const long B1 = B0 + 384L * 1024;
        const long B2 = B1 + 8064L * 256;
        const long B3 = B2 + 40320L * 64;
        long e = ((long)bid * 256 + threadIdx.x) * 4;
        if (e >= B3) return;
        const float* src; unsigned short* dst; long rows; int colshift; long base;
        float sc;
        if (e < B0)      { base = 0;  src = hw;  dst = hWb;  rows = 2002;  colshift = 10; sc = L2E; }
        else if (e < B1) {
            long l = e - B0;
            long row = l >> 10;
            unsigned short* d = pW01 + l;
            ushort4 o;
            if (row < 256) {
                float4 v = *reinterpret_cast<const float4*>(p0w + l);
                o = make_ushort4(f2bf(v.x), f2bf(v.y), f2bf(v.z), f2bf(v.w));
            } else if (row < 320) {
                float4 v = *reinterpret_cast<const float4*>(p1w + (l - 256L * 1024));
                o = make_ushort4(f2bf(v.x), f2bf(v.y), f2bf(v.z), f2bf(v.w));
            } else {
                o = make_ushort4(0, 0, 0, 0);
            }
            *reinterpret_cast<ushort4*>(d) = o;
            return;
        }
        else if (e < B2) { base = B1; src = o0w; dst = o0Wb; rows = 8000;  colshift = 8; sc = L2E; }
        else             { base = B2; src = o1w; dst = o1Wb; rows = 40257; colshift = 6; sc = L2E; }
        long l = e - base;
        long row = l >> colshift;
        ushort4 o;
        if (row < rows) {
            float4 v = *reinterpret_cast<const float4*>(src + l);
            o = make_ushort4(f2bf(v.x * sc), f2bf(v.y * sc), f2bf(v.z * sc), f2bf(v.w * sc));
        } else {
            o = make_ushort4(0, 0, 0, 0);
        }
        *reinterpret_cast<ushort4*>(dst + l) = o;
        return;
    }
    bid -= 6968;                           // ---- prep (8 blocks)
    int n = bid * 256 + threadIdx.x;
    if (n >= 2048) return;
    bias_s[n] = (n < 2002) ? hb[n] * L2E : -1e30f;
    int t = tgt[n];
    tc[n] = min(t, 1999);
    tc[2048 + n] = min(max(t - 2000, 0), 7999);
    tc[4096 + n] = min(max(t - 10000, 0), 40256);
}

// ---------------- 128x128-tile GEMM, BK=64, T3-minimum dbuf + T2 XOR swizzle ------
template <int NT>
__global__ __launch_bounds__(256)
void k_mm(const unsigned short* __restrict__ A, int lda,
          const unsigned short* __restrict__ B, int ldb,
          const float* __restrict__ bias, float* __restrict__ partial,
          unsigned short* __restrict__ hout, int hstride, int hcols, int fsplit) {
    __shared__ unsigned short As[2][128 * 64];
    __shared__ unsigned short Bs[2][128 * 64];
    const int tid = threadIdx.x;
    const int lane = tid & 63, wid = tid >> 6;
    const int wr = wid >> 1, wc = wid & 1;
    const int g = lane >> 4, cl = lane & 15;
    const int row0 = blockIdx.x * 128;
    const int col0 = blockIdx.y * 128;

    const int sr = wid * 8 + (lane >> 3);                  // staging row 0..31 (+i*32)
    const int swz = ((lane & 7) ^ (lane >> 3)) * 8;        // pre-swizzled k-slot (elems)
    const unsigned short* Ab = A + (size_t)(row0 + sr) * lda + swz;
    const unsigned short* Bb = B + (size_t)(col0 + sr) * ldb + swz;

    auto stage = [&](int buf, int kt) {
        const unsigned short* ga = Ab + kt;
        const unsigned short* gb = Bb + kt;
        unsigned short* la = &As[buf][wid * 8 * 64];
        unsigned short* lb = &Bs[buf][wid * 8 * 64];
#pragma unroll
        for (int i = 0; i < 4; ++i) {
            __builtin_amdgcn_global_load_lds((gas_t)(const void*)(ga + (size_t)i * 32 * lda),
                                             (las_t)(void*)(la + i * 32 * 64), 16, 0, 0);
            __builtin_amdgcn_global_load_lds((gas_t)(const void*)(gb + (size_t)i * 32 * ldb),
                                             (las_t)(void*)(lb + i * 32 * 64), 16, 0, 0);
        }
    };

    f32x4 acc[4][4] = {};
    stage(0, 0);
    asm volatile("s_waitcnt vmcnt(0)" ::: "memory");
    __builtin_amdgcn_s_barrier();
    const int sA = (cl & 7);                               // read-side XOR (row&7 == cl&7)
    for (int t = 0; t < NT; ++t) {
        if (t + 1 < NT) stage((t + 1) & 1, (t + 1) * 64);
        const unsigned short* Al = &As[t & 1][(wr * 64 + cl) * 64];
        const unsigned short* Bl = &Bs[t & 1][(wc * 64 + cl) * 64];
#pragma unroll
        for (int kk2 = 0; kk2 < 2; ++kk2) {
            const int slot = ((kk2 * 4 + g) ^ sA) * 8;
            s16x8 a[4], b[4];
#pragma unroll
            for (int mi = 0; mi < 4; ++mi)
                a[mi] = *reinterpret_cast<const s16x8*>(Al + mi * 16 * 64 + slot);
#pragma unroll
            for (int ni = 0; ni < 4; ++ni)
                b[ni] = *reinterpret_cast<const s16x8*>(Bl + ni * 16 * 64 + slot);
#pragma unroll
            for (int mi = 0; mi < 4; ++mi)
#pragma unroll
                for (int ni = 0; ni < 4; ++ni)
                    acc[mi][ni] = mfma16(a[mi], b[ni], acc[mi][ni]);
        }
        if (t + 1 < NT) {
            asm volatile("s_waitcnt vmcnt(0)" ::: "memory");
            __builtin_amdgcn_s_barrier();
        }
    }

    if ((int)blockIdx.y >= fsplit) {
        int c0 = col0 - fsplit * 128;
#pragma unroll
        for (int mi = 0; mi < 4; ++mi)
#pragma unroll
            for (int ni = 0; ni < 4; ++ni) {
                int col = c0 + wc * 64 + ni * 16 + cl;
                if (col < hcols) {
#pragma unroll
                    for (int r = 0; r < 4; ++r) {
                        int row = row0 + wr * 64 + mi * 16 + g * 4 + r;
                        hout[(size_t)row * hstride + col] = f2bf(acc[mi][ni][r]);
                    }
                }
            }
    } else {
        float bv[4];
#pragma unroll
        for (int ni = 0; ni < 4; ++ni)
            bv[ni] = bias ? bias[col0 + wc * 64 + ni * 16 + cl] : 0.f;
        int strip = blockIdx.y * 2 + wc;
#pragma unroll
        for (int mi = 0; mi < 4; ++mi)
#pragma unroll
            for (int r = 0; r < 4; ++r) {
                float s = 0.f;
#pragma unroll
                for (int ni = 0; ni < 4; ++ni)
                    s += __builtin_amdgcn_exp2f(acc[mi][ni][r] + bv[ni]);
                s += __shfl_xor(s, 1, 64);
                s += __shfl_xor(s, 2, 64);
                s += __shfl_xor(s, 4, 64);
                s += __shfl_xor(s, 8, 64);
                if (cl == 0)
                    partial[(size_t)strip * NROWS + row0 + wr * 64 + mi * 16 + g * 4 + r] = s;
            }
    }
}

// ---------------- out1 v5: K=64 A in regs, B via 2-buf LDS, 5 col-tiles/block ------
// __launch_bounds__(256,4) caps VGPR at 128; #pragma unroll 1 prevents the
// unroll-driven register blowup (R6: VGPR=256, occupancy 8.7%).
#define OUT1_IT 5
__global__ __launch_bounds__(256, 4)
void k_out1(const unsigned short* __restrict__ h01, const unsigned short* __restrict__ B,
            float* __restrict__ p1) {
    __shared__ unsigned short Bs[2][128 * 64];
    const int tid = threadIdx.x;
    const int lane = tid & 63, wid = tid >> 6;
    const int wr = wid >> 1, wc = wid & 1;
    const int g = lane >> 4, cl = lane & 15;
    const int row0 = blockIdx.x * 128 + wr * 64;
    const int t0 = blockIdx.y * OUT1_IT;

    s16x8 a[4][2];
#pragma unroll
    for (int mi = 0; mi < 4; ++mi)
#pragma unroll
        for (int kk = 0; kk < 2; ++kk)
            a[mi][kk] = *reinterpret_cast<const s16x8*>(
                h01 + (size_t)(row0 + mi * 16 + cl) * 320 + 256 + kk * 32 + g * 8);

    const int sr = wid * 8 + (lane >> 3);                  // B row within tile
    const int swz = ((lane & 7) ^ (lane >> 3)) * 8;        // pre-swizzled k-slot
    auto stage = [&](int buf, int tile) {
        const unsigned short* gb = B + ((size_t)tile * 128 + sr) * 64 + swz;
        unsigned short* lb = &Bs[buf][wid * 8 * 64];
#pragma unroll
        for (int i = 0; i < 4; ++i)
            __builtin_amdgcn_global_load_lds((gas_t)(const void*)(gb + (size_t)i * 32 * 64),
                                             (las_t)(void*)(lb + i * 32 * 64), 16, 0, 0);
    };

    float sexp[4][4] = {};
    const f32x4 z4 = {0.f, 0.f, 0.f, 0.f};
    stage(0, t0);
    asm volatile("s_waitcnt vmcnt(0)" ::: "memory");
    __builtin_amdgcn_s_barrier();
    int buf = 0;
    const int sA = (cl & 7);
#pragma unroll 1
    for (int it = 0; it < OUT1_IT; ++it) {
        if (it + 1 < OUT1_IT) stage(buf ^ 1, t0 + it + 1);
        const unsigned short* Bl = Bs[buf];
#pragma unroll
        for (int ni = 0; ni < 4; ++ni) {
            const unsigned short* br = Bl + (wc * 64 + ni * 16 + cl) * 64;
            s16x8 b0 = *reinterpret_cast<const s16x8*>(br + (g ^ sA) * 8);
            s16x8 b1 = *reinterpret_cast<const s16x8*>(br + ((4 + g) ^ sA) * 8);
            f32x4 acc[4];
#pragma unroll
            for (int mi = 0; mi < 4; ++mi)
                acc[mi] = mfma16(a[mi][0], b0, z4);
#pragma unroll
            for (int mi = 0; mi < 4; ++mi)
                acc[mi] = mfma16(a[mi][1], b1, acc[mi]);
#pragma unroll
            for (int mi = 0; mi < 4; ++mi)
#pragma unroll
                for (int r = 0; r < 4; ++r)
                    sexp[mi][r] += __builtin_amdgcn_exp2f(acc[mi][r]);
        }
        if (it + 1 < OUT1_IT) {
            asm volatile("s_waitcnt vmcnt(0)" ::: "memory");
            __builtin_amdgcn_s_barrier();
            buf ^= 1;
        }
    }

#pragma unroll
    for (int mi = 0; mi < 4; ++mi)
#pragma unroll
        for (int r = 0; r < 4; ++r) {
            float s = sexp[mi][r];
            s += __shfl_xor(s, 1, 64);
            s += __shfl_xor(s, 2, 64);
            s += __shfl_xor(s, 4, 64);
            s += __shfl_xor(s, 8, 64);
            if (cl == 0)
                p1[(size_t)(blockIdx.y * 2 + wc) * NROWS + row0 + mi * 16 + g * 4 + r] = s;
        }
}

// ---------------- per-row target / routing dots ----------------
__global__ __launch_bounds__(256)
void k_dots(const unsigned short* __restrict__ xb, const unsigned short* __restrict__ h01,
            const float* __restrict__ headW, const float* __restrict__ hb,
            const float* __restrict__ o0w, const float* __restrict__ o1w,
            const int* __restrict__ tc,
            float* __restrict__ tgh, float* __restrict__ r0, float* __restrict__ r1,
            float* __restrict__ tg0, float* __restrict__ tg1) {
    int lane = threadIdx.x & 63;
    int n = (blockIdx.x * 256 + threadIdx.x) >> 6;
    int tch = tc[n], tc0 = tc[2048 + n], tc1 = tc[4096 + n];
    const unsigned short* xr = xb + (size_t)n * 1024 + lane * 16;
    s16x8 x0 = *reinterpret_cast<const s16x8*>(xr);
    s16x8 x1 = *reinterpret_cast<const s16x8*>(xr + 8);
    const float* wh = headW + (size_t)tch * 1024 + lane * 16;
    const float* wa = headW + (size_t)2000 * 1024 + lane * 16;
    const float* wb = headW + (size_t)2001 * 1024 + lane * 16;
    float dh = 0.f, da = 0.f, db = 0.f;
#pragma unroll
    for (int i = 0; i < 8; ++i) {
        float xv = bf2f((unsigned short)x0[i]);
        dh += xv * wh[i]; da += xv * wa[i]; db += xv * wb[i];
    }
#pragma unroll
    for (int i = 0; i < 8; ++i) {
        float xv = bf2f((unsigned short)x1[i]);
        dh += xv * wh[8 + i]; da += xv * wa[8 + i]; db += xv * wb[8 + i];
    }
    ushort4 h0v = *reinterpret_cast<const ushort4*>(h01 + (size_t)n * 320 + lane * 4);
    float4 w0v = *reinterpret_cast<const float4*>(o0w + (size_t)tc0 * 256 + lane * 4);
    float d2 = bf2f(h0v.x) * w0v.x + bf2f(h0v.y) * w0v.y +
               bf2f(h0v.z) * w0v.z + bf2f(h0v.w) * w0v.w;
    float d3 = bf2f(h01[(size_t)n * 320 + 256 + lane]) * o1w[(size_t)tc1 * 64 + lane];
#pragma unroll
    for (int m = 1; m < 64; m <<= 1) {
        dh += __shfl_xor(dh, m, 64);
        da += __shfl_xor(da, m, 64);
        db += __shfl_xor(db, m, 64);
        d2 += __shfl_xor(d2, m, 64);
        d3 += __shfl_xor(d3, m, 64);
    }
    if (lane == 0) {
        tgh[n] = dh + hb[tch];
        r0[n] = da + hb[2000];
        r1[n] = db + hb[2001];
        tg0[n] = d2;
        tg1[n] = d3;
    }
}

// ---------------- finalize ----------------
__global__ void k_finalize(const float* __restrict__ ph, const float* __restrict__ p0,
                           const float* __restrict__ p1, const float* __restrict__ tgh,
                           const float* __restrict__ r0, const float* __restrict__ r1,
                           const float* __restrict__ tg0, const float* __restrict__ tg1,
                           const int* __restrict__ tgt, float* __restrict__ outv,
                           float* __restrict__ bsum) {
    int n = blockIdx.x * 128 + threadIdx.x;   // 16 blocks x 128
    float sh = 0.f, s0 = 0.f, s1 = 0.f;
    for (int s = 0; s < 32; ++s) sh += ph[(size_t)s * NROWS + n];
    for (int s = 0; s < 126; ++s) s0 += p0[(size_t)s * NROWS + n];
    for (int s = 0; s < 126; ++s) s1 += p1[(size_t)s * NROWS + n];
    s0 -= 64.f;   // zero-weight pad cols contribute exp2(0)=1 each
    s1 -= 63.f;
    float lh = __logf(sh), l0 = __logf(s0), l1 = __logf(s1);
    int t = tgt[n];
    float o;
    if (t < 2000) o = tgh[n] - lh;
    else if (t < 10000) o = (r0[n] - lh) + (tg0[n] - l0);
    else o = (r1[n] - lh) + (tg1[n] - l1);
    outv[n] = o;
    __shared__ float red[128];
    red[threadIdx.x] = o;
    __syncthreads();
    for (int s = 64; s > 0; s >>= 1) {
        if (threadIdx.x < s) red[threadIdx.x] += red[threadIdx.x + s];
        __syncthreads();
    }
    if (threadIdx.x == 0) bsum[blockIdx.x] = red[0];
}

__global__ void k_loss(const float* __restrict__ bsum, float* __restrict__ loss) {
    float s = 0.f;
    for (int i = 0; i < 16; ++i) s += bsum[i];
    *loss = -s / (float)NROWS;
}

extern "C" void kernel_launch(void* const* d_in, const int* in_sizes, int n_in,
                              void* d_out, int out_size, void* d_ws, size_t ws_size,
                              hipStream_t stream) {
    const int* targets   = (const int*)d_in[0];
    const float* lhs     = (const float*)d_in[1];
    const int* idx       = (const int*)d_in[3];
    const float* head_W  = (const float*)d_in[4];
    const float* head_b  = (const float*)d_in[5];
    const float* proj0_W = (const float*)d_in[6];
    const float* out0_W  = (const float*)d_in[7];
    const float* proj1_W = (const float*)d_in[8];
    const float* out1_W  = (const float*)d_in[9];

    char* ws = (char*)d_ws;
    size_t off = 0;
    auto alloc = [&](size_t bytes) -> void* {
        void* p = ws + off;
        off += (bytes + 255) & ~(size_t)255;
        return p;
    };

    unsigned short* xb   = (unsigned short*)alloc((size_t)2048 * 1024 * 2);
    unsigned short* wB   = (unsigned short*)alloc((size_t)2432 * 1024 * 2);
    unsigned short* hWb  = wB;
    unsigned short* pW01 = wB + (size_t)2048 * 1024;
    unsigned short* o0Wb = (unsigned short*)alloc((size_t)8064 * 256 * 2);
    unsigned short* o1Wb = (unsigned short*)alloc((size_t)40320 * 64 * 2);
    unsigned short* h01  = (unsigned short*)alloc((size_t)2048 * 320 * 2);
    float* ph  = (float*)alloc((size_t)32 * 2048 * 4);
    float* p0  = (float*)alloc((size_t)126 * 2048 * 4);
    float* p1  = (float*)alloc((size_t)126 * 2048 * 4);
    float* tgh = (float*)alloc(2048 * 4);
    float* r0  = (float*)alloc(2048 * 4);
    float* r1  = (float*)alloc(2048 * 4);
    float* tg0 = (float*)alloc(2048 * 4);
    float* tg1 = (float*)alloc(2048 * 4);
    int*   tc  = (int*)alloc(3 * 2048 * 4);
    float* bias_s = (float*)alloc(2048 * 4);
    float* bsum = (float*)alloc(16 * 4);

    // merged gather + convert + prep: 2048 + 6968 + 8 blocks
    k_prologue<<<9024, 256, 0, stream>>>(lhs, idx, head_W, proj0_W, proj1_W, out0_W, out1_W,
                                         head_b, targets,
                                         xb, hWb, pW01, o0Wb, o1Wb, bias_s, tc);

    // head (y<16: fused exp2-sum, 32 strips) + proj (y>=16: store h01) in ONE launch
    k_mm<16><<<dim3(16, 19), 256, 0, stream>>>(
        xb, 1024, wB, 1024, bias_s, ph, h01, 320, 320, 16);
    // out0: 2048 x 8064, K=256, fused exp2-sum (126 strips)
    k_mm<4><<<dim3(16, 63), 256, 0, stream>>>(
        h01, 320, o0Wb, 256, nullptr, p0, nullptr, 0, 0, 63);
    // out1: 2048 x 40320, K=64, fused exp2-sum (126 strips, 5 tiles/block)
    k_out1<<<dim3(16, 63), 256, 0, stream>>>(h01, o1Wb, p1);

    k_dots<<<512, 256, 0, stream>>>(xb, h01, head_W, head_b, out0_W, out1_W, tc,
                                    tgh, r0, r1, tg0, tg1);

    float* outv = (float*)d_out;
    float* loss = (float*)d_out + NROWS;
    k_finalize<<<16, 128, 0, stream>>>(ph, p0, p1, tgh, r0, r1, tg0, tg1, targets, outv, bsum);
    k_loss<<<1, 1, 0, stream>>>(bsum, loss);
}

// Round 8
// 92.385 us; speedup vs baseline: 1.8094x; 1.0001x over previous
//
#include <hip/hip_runtime.h>
#include <hip/hip_bf16.h>

#define NROWS 2048
#define L2E 1.4426950408889634f

typedef float f32x4 __attribute__((ext_vector_type(4)));
typedef __bf16 bf16x8 __attribute__((ext_vector_type(8)));
typedef short s16x8 __attribute__((ext_vector_type(8)));

typedef const __attribute__((address_space(1))) unsigned int* gas_t;
typedef __attribute__((address_space(3))) unsigned int* las_t;

__device__ __forceinline__ unsigned short f2bf(float f) {
    unsigned int u = __float_as_uint(f);
    unsigned int r = (u + 0x7FFFu + ((u >> 16) & 1u)) >> 16;
    return (unsigned short)r;
}
__device__ __forceinline__ float bf2f(unsigned short u) {
    return __uint_as_float((unsigned int)u << 16);
}
__device__ __forceinline__ f32x4 mfma16(s16x8 a, s16x8 b, f32x4 c) {
    return __builtin_amdgcn_mfma_f32_16x16x32_bf16(
        __builtin_bit_cast(bf16x8, a), __builtin_bit_cast(bf16x8, b), c, 0, 0, 0);
}

// ---------------- merged prologue: gather x | convert weights | prep ----------------
__global__ void k_prologue(const float* __restrict__ lhs, const int* __restrict__ idx,
                           const float* __restrict__ hw, const float* __restrict__ p0w,
                           const float* __restrict__ p1w, const float* __restrict__ o0w,
                           const float* __restrict__ o1w, const float* __restrict__ hb,
                           const int* __restrict__ tgt,
                           unsigned short* __restrict__ xb, unsigned short* __restrict__ hWb,
                           unsigned short* __restrict__ pW01, unsigned short* __restrict__ o0Wb,
                           unsigned short* __restrict__ o1Wb,
                           float* __restrict__ bias_s, int* __restrict__ tc) {
    int bid = blockIdx.x;
    if (bid < 2048) {                      // ---- gather x: 2048 rows x 1024 cols bf16
        int tid = bid * 256 + threadIdx.x;
        int n = tid >> 8;
        int c = (tid & 255) << 2;
        int b = n >> 8, k = n & 255;
        int srow = idx[(b << 8) + k];
        const float4 v = *reinterpret_cast<const float4*>(
            lhs + (((size_t)b << 9) + srow) * 1024 + c);
        ushort4 o = make_ushort4(f2bf(v.x), f2bf(v.y), f2bf(v.z), f2bf(v.w));
        *reinterpret_cast<ushort4*>(xb + (size_t)n * 1024 + c) = o;
        return;
    }
    bid -= 2048;
    if (bid < 6968) {                      // ---- weight conversion (exp-weights * log2e)
        const long B0 = 2048L * 1024;
        const long B1 = B0 + 384L * 1024;
        const long B2 = B1 + 8064L * 256;
        const long B3 = B2 + 40320L * 64;
        long e = ((long)bid * 256 + threadIdx.x) * 4;
        if (e >= B3) return;
        const float* src; unsigned short* dst; long rows; int colshift; long base;
        float sc;
        if (e < B0)      { base = 0;  src = hw;  dst = hWb;  rows = 2002;  colshift = 10; sc = L2E; }
        else if (e < B1) {
            long l = e - B0;
            long row = l >> 10;
            unsigned short* d = pW01 + l;
            ushort4 o;
            if (row < 256) {
                float4 v = *reinterpret_cast<const float4*>(p0w + l);
                o = make_ushort4(f2bf(v.x), f2bf(v.y), f2bf(v.z), f2bf(v.w));
            } else if (row < 320) {
                float4 v = *reinterpret_cast<const float4*>(p1w + (l - 256L * 1024));
                o = make_ushort4(f2bf(v.x), f2bf(v.y), f2bf(v.z), f2bf(v.w));
            } else {
                o = make_ushort4(0, 0, 0, 0);
            }
            *reinterpret_cast<ushort4*>(d) = o;
            return;
        }
        else if (e < B2) { base = B1; src = o0w; dst = o0Wb; rows = 8000;  colshift = 8; sc = L2E; }
        else             { base = B2; src = o1w; dst = o1Wb; rows = 40257; colshift = 6; sc = L2E; }
        long l = e - base;
        long row = l >> colshift;
        ushort4 o;
        if (row < rows) {
            float4 v = *reinterpret_cast<const float4*>(src + l);
            o = make_ushort4(f2bf(v.x * sc), f2bf(v.y * sc), f2bf(v.z * sc), f2bf(v.w * sc));
        } else {
            o = make_ushort4(0, 0, 0, 0);
        }
        *reinterpret_cast<ushort4*>(dst + l) = o;
        return;
    }
    bid -= 6968;                           // ---- prep (8 blocks)
    int n = bid * 256 + threadIdx.x;
    if (n >= 2048) return;
    bias_s[n] = (n < 2002) ? hb[n] * L2E : -1e30f;
    int t = tgt[n];
    tc[n] = min(t, 1999);
    tc[2048 + n] = min(max(t - 2000, 0), 7999);
    tc[4096 + n] = min(max(t - 10000, 0), 40256);
}

// ---------------- 128x128-tile GEMM, BK=64, T3-minimum dbuf + T2 XOR swizzle ------
template <int NT>
__global__ __launch_bounds__(256)
void k_mm(const unsigned short* __restrict__ A, int lda,
          const unsigned short* __restrict__ B, int ldb,
          const float* __restrict__ bias, float* __restrict__ partial,
          unsigned short* __restrict__ hout, int hstride, int hcols, int fsplit) {
    __shared__ unsigned short As[2][128 * 64];
    __shared__ unsigned short Bs[2][128 * 64];
    const int tid = threadIdx.x;
    const int lane = tid & 63, wid = tid >> 6;
    const int wr = wid >> 1, wc = wid & 1;
    const int g = lane >> 4, cl = lane & 15;
    const int row0 = blockIdx.x * 128;
    const int col0 = blockIdx.y * 128;

    const int sr = wid * 8 + (lane >> 3);                  // staging row 0..31 (+i*32)
    const int swz = ((lane & 7) ^ (lane >> 3)) * 8;        // pre-swizzled k-slot (elems)
    const unsigned short* Ab = A + (size_t)(row0 + sr) * lda + swz;
    const unsigned short* Bb = B + (size_t)(col0 + sr) * ldb + swz;

    auto stage = [&](int buf, int kt) {
        const unsigned short* ga = Ab + kt;
        const unsigned short* gb = Bb + kt;
        unsigned short* la = &As[buf][wid * 8 * 64];
        unsigned short* lb = &Bs[buf][wid * 8 * 64];
#pragma unroll
        for (int i = 0; i < 4; ++i) {
            __builtin_amdgcn_global_load_lds((gas_t)(const void*)(ga + (size_t)i * 32 * lda),
                                             (las_t)(void*)(la + i * 32 * 64), 16, 0, 0);
            __builtin_amdgcn_global_load_lds((gas_t)(const void*)(gb + (size_t)i * 32 * ldb),
                                             (las_t)(void*)(lb + i * 32 * 64), 16, 0, 0);
        }
    };

    f32x4 acc[4][4] = {};
    stage(0, 0);
    asm volatile("s_waitcnt vmcnt(0)" ::: "memory");
    __builtin_amdgcn_s_barrier();
    const int sA = (cl & 7);                               // read-side XOR (row&7 == cl&7)
    for (int t = 0; t < NT; ++t) {
        if (t + 1 < NT) stage((t + 1) & 1, (t + 1) * 64);
        const unsigned short* Al = &As[t & 1][(wr * 64 + cl) * 64];
        const unsigned short* Bl = &Bs[t & 1][(wc * 64 + cl) * 64];
#pragma unroll
        for (int kk2 = 0; kk2 < 2; ++kk2) {
            const int slot = ((kk2 * 4 + g) ^ sA) * 8;
            s16x8 a[4], b[4];
#pragma unroll
            for (int mi = 0; mi < 4; ++mi)
                a[mi] = *reinterpret_cast<const s16x8*>(Al + mi * 16 * 64 + slot);
#pragma unroll
            for (int ni = 0; ni < 4; ++ni)
                b[ni] = *reinterpret_cast<const s16x8*>(Bl + ni * 16 * 64 + slot);
#pragma unroll
            for (int mi = 0; mi < 4; ++mi)
#pragma unroll
                for (int ni = 0; ni < 4; ++ni)
                    acc[mi][ni] = mfma16(a[mi], b[ni], acc[mi][ni]);
        }
        if (t + 1 < NT) {
            asm volatile("s_waitcnt vmcnt(0)" ::: "memory");
            __builtin_amdgcn_s_barrier();
        }
    }

    if ((int)blockIdx.y >= fsplit) {
        int c0 = col0 - fsplit * 128;
#pragma unroll
        for (int mi = 0; mi < 4; ++mi)
#pragma unroll
            for (int ni = 0; ni < 4; ++ni) {
                int col = c0 + wc * 64 + ni * 16 + cl;
                if (col < hcols) {
#pragma unroll
                    for (int r = 0; r < 4; ++r) {
                        int row = row0 + wr * 64 + mi * 16 + g * 4 + r;
                        hout[(size_t)row * hstride + col] = f2bf(acc[mi][ni][r]);
                    }
                }
            }
    } else {
        float bv[4];
#pragma unroll
        for (int ni = 0; ni < 4; ++ni)
            bv[ni] = bias ? bias[col0 + wc * 64 + ni * 16 + cl] : 0.f;
        int strip = blockIdx.y * 2 + wc;
#pragma unroll
        for (int mi = 0; mi < 4; ++mi)
#pragma unroll
            for (int r = 0; r < 4; ++r) {
                float s = 0.f;
#pragma unroll
                for (int ni = 0; ni < 4; ++ni)
                    s += __builtin_amdgcn_exp2f(acc[mi][ni][r] + bv[ni]);
                s += __shfl_xor(s, 1, 64);
                s += __shfl_xor(s, 2, 64);
                s += __shfl_xor(s, 4, 64);
                s += __shfl_xor(s, 8, 64);
                if (cl == 0)
                    partial[(size_t)strip * NROWS + row0 + wr * 64 + mi * 16 + g * 4 + r] = s;
            }
    }
}

// ---------------- out1 v5: K=64 A in regs, B via 2-buf LDS, 5 col-tiles/block ------
// __launch_bounds__(256,4) caps VGPR at 128; #pragma unroll 1 prevents the
// unroll-driven register blowup (R6: VGPR=256, occupancy 8.7%).
#define OUT1_IT 5
__global__ __launch_bounds__(256, 4)
void k_out1(const unsigned short* __restrict__ h01, const unsigned short* __restrict__ B,
            float* __restrict__ p1) {
    __shared__ unsigned short Bs[2][128 * 64];
    const int tid = threadIdx.x;
    const int lane = tid & 63, wid = tid >> 6;
    const int wr = wid >> 1, wc = wid & 1;
    const int g = lane >> 4, cl = lane & 15;
    const int row0 = blockIdx.x * 128 + wr * 64;
    const int t0 = blockIdx.y * OUT1_IT;

    s16x8 a[4][2];
#pragma unroll
    for (int mi = 0; mi < 4; ++mi)
#pragma unroll
        for (int kk = 0; kk < 2; ++kk)
            a[mi][kk] = *reinterpret_cast<const s16x8*>(
                h01 + (size_t)(row0 + mi * 16 + cl) * 320 + 256 + kk * 32 + g * 8);

    const int sr = wid * 8 + (lane >> 3);                  // B row within tile
    const int swz = ((lane & 7) ^ (lane >> 3)) * 8;        // pre-swizzled k-slot
    auto stage = [&](int buf, int tile) {
        const unsigned short* gb = B + ((size_t)tile * 128 + sr) * 64 + swz;
        unsigned short* lb = &Bs[buf][wid * 8 * 64];
#pragma unroll
        for (int i = 0; i < 4; ++i)
            __builtin_amdgcn_global_load_lds((gas_t)(const void*)(gb + (size_t)i * 32 * 64),
                                             (las_t)(void*)(lb + i * 32 * 64), 16, 0, 0);
    };

    float sexp[4][4] = {};
    const f32x4 z4 = {0.f, 0.f, 0.f, 0.f};
    stage(0, t0);
    asm volatile("s_waitcnt vmcnt(0)" ::: "memory");
    __builtin_amdgcn_s_barrier();
    int buf = 0;
    const int sA = (cl & 7);
#pragma unroll 1
    for (int it = 0; it < OUT1_IT; ++it) {
        if (it + 1 < OUT1_IT) stage(buf ^ 1, t0 + it + 1);
        const unsigned short* Bl = Bs[buf];
#pragma unroll
        for (int ni = 0; ni < 4; ++ni) {
            const unsigned short* br = Bl + (wc * 64 + ni * 16 + cl) * 64;
            s16x8 b0 = *reinterpret_cast<const s16x8*>(br + (g ^ sA) * 8);
            s16x8 b1 = *reinterpret_cast<const s16x8*>(br + ((4 + g) ^ sA) * 8);
            f32x4 acc[4];
#pragma unroll
            for (int mi = 0; mi < 4; ++mi)
                acc[mi] = mfma16(a[mi][0], b0, z4);
#pragma unroll
            for (int mi = 0; mi < 4; ++mi)
                acc[mi] = mfma16(a[mi][1], b1, acc[mi]);
#pragma unroll
            for (int mi = 0; mi < 4; ++mi)
#pragma unroll
                for (int r = 0; r < 4; ++r)
                    sexp[mi][r] += __builtin_amdgcn_exp2f(acc[mi][r]);
        }
        if (it + 1 < OUT1_IT) {
            asm volatile("s_waitcnt vmcnt(0)" ::: "memory");
            __builtin_amdgcn_s_barrier();
            buf ^= 1;
        }
    }

#pragma unroll
    for (int mi = 0; mi < 4; ++mi)
#pragma unroll
        for (int r = 0; r < 4; ++r) {
            float s = sexp[mi][r];
            s += __shfl_xor(s, 1, 64);
            s += __shfl_xor(s, 2, 64);
            s += __shfl_xor(s, 4, 64);
            s += __shfl_xor(s, 8, 64);
            if (cl == 0)
                p1[(size_t)(blockIdx.y * 2 + wc) * NROWS + row0 + mi * 16 + g * 4 + r] = s;
        }
}

// ---------------- per-row target / routing dots ----------------
__global__ __launch_bounds__(256)
void k_dots(const unsigned short* __restrict__ xb, const unsigned short* __restrict__ h01,
            const float* __restrict__ headW, const float* __restrict__ hb,
            const float* __restrict__ o0w, const float* __restrict__ o1w,
            const int* __restrict__ tc,
            float* __restrict__ tgh, float* __restrict__ r0, float* __restrict__ r1,
            float* __restrict__ tg0, float* __restrict__ tg1) {
    int lane = threadIdx.x & 63;
    int n = (blockIdx.x * 256 + threadIdx.x) >> 6;
    int tch = tc[n], tc0 = tc[2048 + n], tc1 = tc[4096 + n];
    const unsigned short* xr = xb + (size_t)n * 1024 + lane * 16;
    s16x8 x0 = *reinterpret_cast<const s16x8*>(xr);
    s16x8 x1 = *reinterpret_cast<const s16x8*>(xr + 8);
    const float* wh = headW + (size_t)tch * 1024 + lane * 16;
    const float* wa = headW + (size_t)2000 * 1024 + lane * 16;
    const float* wb = headW + (size_t)2001 * 1024 + lane * 16;
    float dh = 0.f, da = 0.f, db = 0.f;
#pragma unroll
    for (int i = 0; i < 8; ++i) {
        float xv = bf2f((unsigned short)x0[i]);
        dh += xv * wh[i]; da += xv * wa[i]; db += xv * wb[i];
    }
#pragma unroll
    for (int i = 0; i < 8; ++i) {
        float xv = bf2f((unsigned short)x1[i]);
        dh += xv * wh[8 + i]; da += xv * wa[8 + i]; db += xv * wb[8 + i];
    }
    ushort4 h0v = *reinterpret_cast<const ushort4*>(h01 + (size_t)n * 320 + lane * 4);
    float4 w0v = *reinterpret_cast<const float4*>(o0w + (size_t)tc0 * 256 + lane * 4);
    float d2 = bf2f(h0v.x) * w0v.x + bf2f(h0v.y) * w0v.y +
               bf2f(h0v.z) * w0v.z + bf2f(h0v.w) * w0v.w;
    float d3 = bf2f(h01[(size_t)n * 320 + 256 + lane]) * o1w[(size_t)tc1 * 64 + lane];
#pragma unroll
    for (int m = 1; m < 64; m <<= 1) {
        dh += __shfl_xor(dh, m, 64);
        da += __shfl_xor(da, m, 64);
        db += __shfl_xor(db, m, 64);
        d2 += __shfl_xor(d2, m, 64);
        d3 += __shfl_xor(d3, m, 64);
    }
    if (lane == 0) {
        tgh[n] = dh + hb[tch];
        r0[n] = da + hb[2000];
        r1[n] = db + hb[2001];
        tg0[n] = d2;
        tg1[n] = d3;
    }
}

// ---------------- finalize ----------------
__global__ void k_finalize(const float* __restrict__ ph, const float* __restrict__ p0,
                           const float* __restrict__ p1, const float* __restrict__ tgh,
                           const float* __restrict__ r0, const float* __restrict__ r1,
                           const float* __restrict__ tg0, const float* __restrict__ tg1,
                           const int* __restrict__ tgt, float* __restrict__ outv,
                           float* __restrict__ bsum) {
    int n = blockIdx.x * 128 + threadIdx.x;   // 16 blocks x 128
    float sh = 0.f, s0 = 0.f, s1 = 0.f;
    for (int s = 0; s < 32; ++s) sh += ph[(size_t)s * NROWS + n];
    for (int s = 0; s < 126; ++s) s0 += p0[(size_t)s * NROWS + n];
    for (int s = 0; s < 126; ++s) s1 += p1[(size_t)s * NROWS + n];
    s0 -= 64.f;   // zero-weight pad cols contribute exp2(0)=1 each
    s1 -= 63.f;
    float lh = __logf(sh), l0 = __logf(s0), l1 = __logf(s1);
    int t = tgt[n];
    float o;
    if (t < 2000) o = tgh[n] - lh;
    else if (t < 10000) o = (r0[n] - lh) + (tg0[n] - l0);
    else o = (r1[n] - lh) + (tg1[n] - l1);
    outv[n] = o;
    __shared__ float red[128];
    red[threadIdx.x] = o;
    __syncthreads();
    for (int s = 64; s > 0; s >>= 1) {
        if (threadIdx.x < s) red[threadIdx.x] += red[threadIdx.x + s];
        __syncthreads();
    }
    if (threadIdx.x == 0) bsum[blockIdx.x] = red[0];
}

__global__ void k_loss(const float* __restrict__ bsum, float* __restrict__ loss) {
    float s = 0.f;
    for (int i = 0; i < 16; ++i) s += bsum[i];
    *loss = -s / (float)NROWS;
}

extern "C" void kernel_launch(void* const* d_in, const int* in_sizes, int n_in,
                              void* d_out, int out_size, void* d_ws, size_t ws_size,
                              hipStream_t stream) {
    const int* targets   = (const int*)d_in[0];
    const float* lhs     = (const float*)d_in[1];
    const int* idx       = (const int*)d_in[3];
    const float* head_W  = (const float*)d_in[4];
    const float* head_b  = (const float*)d_in[5];
    const float* proj0_W = (const float*)d_in[6];
    const float* out0_W  = (const float*)d_in[7];
    const float* proj1_W = (const float*)d_in[8];
    const float* out1_W  = (const float*)d_in[9];

    char* ws = (char*)d_ws;
    size_t off = 0;
    auto alloc = [&](size_t bytes) -> void* {
        void* p = ws + off;
        off += (bytes + 255) & ~(size_t)255;
        return p;
    };

    unsigned short* xb   = (unsigned short*)alloc((size_t)2048 * 1024 * 2);
    unsigned short* wB   = (unsigned short*)alloc((size_t)2432 * 1024 * 2);
    unsigned short* hWb  = wB;
    unsigned short* pW01 = wB + (size_t)2048 * 1024;
    unsigned short* o0Wb = (unsigned short*)alloc((size_t)8064 * 256 * 2);
    unsigned short* o1Wb = (unsigned short*)alloc((size_t)40320 * 64 * 2);
    unsigned short* h01  = (unsigned short*)alloc((size_t)2048 * 320 * 2);
    float* ph  = (float*)alloc((size_t)32 * 2048 * 4);
    float* p0  = (float*)alloc((size_t)126 * 2048 * 4);
    float* p1  = (float*)alloc((size_t)126 * 2048 * 4);
    float* tgh = (float*)alloc(2048 * 4);
    float* r0  = (float*)alloc(2048 * 4);
    float* r1  = (float*)alloc(2048 * 4);
    float* tg0 = (float*)alloc(2048 * 4);
    float* tg1 = (float*)alloc(2048 * 4);
    int*   tc  = (int*)alloc(3 * 2048 * 4);
    float* bias_s = (float*)alloc(2048 * 4);
    float* bsum = (float*)alloc(16 * 4);

    // merged gather + convert + prep: 2048 + 6968 + 8 blocks
    k_prologue<<<9024, 256, 0, stream>>>(lhs, idx, head_W, proj0_W, proj1_W, out0_W, out1_W,
                                         head_b, targets,
                                         xb, hWb, pW01, o0Wb, o1Wb, bias_s, tc);

    // head (y<16: fused exp2-sum, 32 strips) + proj (y>=16: store h01) in ONE launch
    k_mm<16><<<dim3(16, 19), 256, 0, stream>>>(
        xb, 1024, wB, 1024, bias_s, ph, h01, 320, 320, 16);
    // out0: 2048 x 8064, K=256, fused exp2-sum (126 strips)
    k_mm<4><<<dim3(16, 63), 256, 0, stream>>>(
        h01, 320, o0Wb, 256, nullptr, p0, nullptr, 0, 0, 63);
    // out1: 2048 x 40320, K=64, fused exp2-sum (126 strips, 5 tiles/block)
    k_out1<<<dim3(16, 63), 256, 0, stream>>>(h01, o1Wb, p1);

    k_dots<<<512, 256, 0, stream>>>(xb, h01, head_W, head_b, out0_W, out1_W, tc,
                                    tgh, r0, r1, tg0, tg1);

    float* outv = (float*)d_out;
    float* loss = (float*)d_out + NROWS;
    k_finalize<<<16, 128, 0, stream>>>(ph, p0, p1, tgh, r0, r1, tg0, tg1, targets, outv, bsum);
    k_loss<<<1, 1, 0, stream>>>(bsum, loss);
}

// Round 9
// 87.528 us; speedup vs baseline: 1.9099x; 1.0555x over previous
//
#include <hip/hip_runtime.h>
#include <hip/hip_bf16.h>

#define NROWS 2048
#define L2E 1.4426950408889634f

typedef float f32x4 __attribute__((ext_vector_type(4)));
typedef __bf16 bf16x8 __attribute__((ext_vector_type(8)));
typedef short s16x8 __attribute__((ext_vector_type(8)));

typedef const __attribute__((address_space(1))) unsigned int* gas_t;
typedef __attribute__((address_space(3))) unsigned int* las_t;

__device__ __forceinline__ unsigned short f2bf(float f) {
    unsigned int u = __float_as_uint(f);
    unsigned int r = (u + 0x7FFFu + ((u >> 16) & 1u)) >> 16;
    return (unsigned short)r;
}
__device__ __forceinline__ float bf2f(unsigned short u) {
    return __uint_as_float((unsigned int)u << 16);
}
__device__ __forceinline__ f32x4 mfma16(s16x8 a, s16x8 b, f32x4 c) {
    return __builtin_amdgcn_mfma_f32_16x16x32_bf16(
        __builtin_bit_cast(bf16x8, a), __builtin_bit_cast(bf16x8, b), c, 0, 0, 0);
}

// ---------------- merged prologue: gather x | convert weights | prep ----------------
__global__ void k_prologue(const float* __restrict__ lhs, const int* __restrict__ idx,
                           const float* __restrict__ hw, const float* __restrict__ p0w,
                           const float* __restrict__ p1w, const float* __restrict__ o0w,
                           const float* __restrict__ o1w, const float* __restrict__ hb,
                           const int* __restrict__ tgt,
                           unsigned short* __restrict__ xb, unsigned short* __restrict__ hWb,
                           unsigned short* __restrict__ pW01, unsigned short* __restrict__ o0Wb,
                           unsigned short* __restrict__ o1Wb,
                           float* __restrict__ bias_s, int* __restrict__ tc) {
    int bid = blockIdx.x;
    if (bid < 2048) {                      // ---- gather x: 2048 rows x 1024 cols bf16
        int tid = bid * 256 + threadIdx.x;
        int n = tid >> 8;
        int c = (tid & 255) << 2;
        int b = n >> 8, k = n & 255;
        int srow = idx[(b << 8) + k];
        const float4 v = *reinterpret_cast<const float4*>(
            lhs + (((size_t)b << 9) + srow) * 1024 + c);
        ushort4 o = make_ushort4(f2bf(v.x), f2bf(v.y), f2bf(v.z), f2bf(v.w));
        *reinterpret_cast<ushort4*>(xb + (size_t)n * 1024 + c) = o;
        return;
    }
    bid -= 2048;
    if (bid < 6968) {                      // ---- weight conversion (exp-weights * log2e)
        const long B0 = 2048L * 1024;
        const long B1 = B0 + 384L * 1024;
        const long B2 = B1 + 8064L * 256;
        const long B3 = B2 + 40320L * 64;
        long e = ((long)bid * 256 + threadIdx.x) * 4;
        if (e >= B3) return;
        const float* src; unsigned short* dst; long rows; int colshift; long base;
        float sc;
        if (e < B0)      { base = 0;  src = hw;  dst = hWb;  rows = 2002;  colshift = 10; sc = L2E; }
        else if (e < B1) {
            long l = e - B0;
            long row = l >> 10;
            unsigned short* d = pW01 + l;
            ushort4 o;
            if (row < 256) {
                float4 v = *reinterpret_cast<const float4*>(p0w + l);
                o = make_ushort4(f2bf(v.x), f2bf(v.y), f2bf(v.z), f2bf(v.w));
            } else if (row < 320) {
                float4 v = *reinterpret_cast<const float4*>(p1w + (l - 256L * 1024));
                o = make_ushort4(f2bf(v.x), f2bf(v.y), f2bf(v.z), f2bf(v.w));
            } else {
                o = make_ushort4(0, 0, 0, 0);
            }
            *reinterpret_cast<ushort4*>(d) = o;
            return;
        }
        else if (e < B2) { base = B1; src = o0w; dst = o0Wb; rows = 8000;  colshift = 8; sc = L2E; }
        else             { base = B2; src = o1w; dst = o1Wb; rows = 40257; colshift = 6; sc = L2E; }
        long l = e - base;
        long row = l >> colshift;
        ushort4 o;
        if (row < rows) {
            float4 v = *reinterpret_cast<const float4*>(src + l);
            o = make_ushort4(f2bf(v.x * sc), f2bf(v.y * sc), f2bf(v.z * sc), f2bf(v.w * sc));
        } else {
            o = make_ushort4(0, 0, 0, 0);
        }
        *reinterpret_cast<ushort4*>(dst + l) = o;
        return;
    }
    bid -= 6968;                           // ---- prep (8 blocks)
    int n = bid * 256 + threadIdx.x;
    if (n >= 2048) return;
    bias_s[n] = (n < 2002) ? hb[n] * L2E : -1e30f;
    int t = tgt[n];
    tc[n] = min(t, 1999);
    tc[2048 + n] = min(max(t - 2000, 0), 7999);
    tc[4096 + n] = min(max(t - 10000, 0), 40256);
}

// ---------------- head+proj: 128x128-tile GEMM, BK=64, dbuf + XOR swizzle ----------
template <int NT>
__global__ __launch_bounds__(256)
void k_mm(const unsigned short* __restrict__ A, int lda,
          const unsigned short* __restrict__ B, int ldb,
          const float* __restrict__ bias, float* __restrict__ partial,
          unsigned short* __restrict__ hout, int hstride, int hcols, int fsplit) {
    __shared__ unsigned short As[2][128 * 64];
    __shared__ unsigned short Bs[2][128 * 64];
    const int tid = threadIdx.x;
    const int lane = tid & 63, wid = tid >> 6;
    const int wr = wid >> 1, wc = wid & 1;
    const int g = lane >> 4, cl = lane & 15;
    const int row0 = blockIdx.x * 128;
    const int col0 = blockIdx.y * 128;

    const int sr = wid * 8 + (lane >> 3);
    const int swz = ((lane & 7) ^ (lane >> 3)) * 8;
    const unsigned short* Ab = A + (size_t)(row0 + sr) * lda + swz;
    const unsigned short* Bb = B + (size_t)(col0 + sr) * ldb + swz;

    auto stage = [&](int buf, int kt) {
        const unsigned short* ga = Ab + kt;
        const unsigned short* gb = Bb + kt;
        unsigned short* la = &As[buf][wid * 8 * 64];
        unsigned short* lb = &Bs[buf][wid * 8 * 64];
#pragma unroll
        for (int i = 0; i < 4; ++i) {
            __builtin_amdgcn_global_load_lds((gas_t)(const void*)(ga + (size_t)i * 32 * lda),
                                             (las_t)(void*)(la + i * 32 * 64), 16, 0, 0);
            __builtin_amdgcn_global_load_lds((gas_t)(const void*)(gb + (size_t)i * 32 * ldb),
                                             (las_t)(void*)(lb + i * 32 * 64), 16, 0, 0);
        }
    };

    f32x4 acc[4][4] = {};
    stage(0, 0);
    asm volatile("s_waitcnt vmcnt(0)" ::: "memory");
    __builtin_amdgcn_s_barrier();
    const int sA = (cl & 7);
    for (int t = 0; t < NT; ++t) {
        if (t + 1 < NT) stage((t + 1) & 1, (t + 1) * 64);
        const unsigned short* Al = &As[t & 1][(wr * 64 + cl) * 64];
        const unsigned short* Bl = &Bs[t & 1][(wc * 64 + cl) * 64];
#pragma unroll
        for (int kk2 = 0; kk2 < 2; ++kk2) {
            const int slot = ((kk2 * 4 + g) ^ sA) * 8;
            s16x8 a[4], b[4];
#pragma unroll
            for (int mi = 0; mi < 4; ++mi)
                a[mi] = *reinterpret_cast<const s16x8*>(Al + mi * 16 * 64 + slot);
#pragma unroll
            for (int ni = 0; ni < 4; ++ni)
                b[ni] = *reinterpret_cast<const s16x8*>(Bl + ni * 16 * 64 + slot);
#pragma unroll
            for (int mi = 0; mi < 4; ++mi)
#pragma unroll
                for (int ni = 0; ni < 4; ++ni)
                    acc[mi][ni] = mfma16(a[mi], b[ni], acc[mi][ni]);
        }
        if (t + 1 < NT) {
            asm volatile("s_waitcnt vmcnt(0)" ::: "memory");
            __builtin_amdgcn_s_barrier();
        }
    }

    if ((int)blockIdx.y >= fsplit) {
        int c0 = col0 - fsplit * 128;
#pragma unroll
        for (int mi = 0; mi < 4; ++mi)
#pragma unroll
            for (int ni = 0; ni < 4; ++ni) {
                int col = c0 + wc * 64 + ni * 16 + cl;
                if (col < hcols) {
#pragma unroll
                    for (int r = 0; r < 4; ++r) {
                        int row = row0 + wr * 64 + mi * 16 + g * 4 + r;
                        hout[(size_t)row * hstride + col] = f2bf(acc[mi][ni][r]);
                    }
                }
            }
    } else {
        float bv[4];
#pragma unroll
        for (int ni = 0; ni < 4; ++ni)
            bv[ni] = bias ? bias[col0 + wc * 64 + ni * 16 + cl] : 0.f;
        int strip = blockIdx.y * 2 + wc;
#pragma unroll
        for (int mi = 0; mi < 4; ++mi)
#pragma unroll
            for (int r = 0; r < 4; ++r) {
                float s = 0.f;
#pragma unroll
                for (int ni = 0; ni < 4; ++ni)
                    s += __builtin_amdgcn_exp2f(acc[mi][ni][r] + bv[ni]);
                s += __shfl_xor(s, 1, 64);
                s += __shfl_xor(s, 2, 64);
                s += __shfl_xor(s, 4, 64);
                s += __shfl_xor(s, 8, 64);
                if (cl == 0)
                    partial[(size_t)strip * NROWS + row0 + wr * 64 + mi * 16 + g * 4 + r] = s;
            }
    }
}

// ---------------- merged tail: out0 (1008) | out1 (1008) | dots (512) ----------------
#define OUT1_IT 5
__global__ __launch_bounds__(256)
void k_tail(const unsigned short* __restrict__ h01, const unsigned short* __restrict__ o0Wb,
            const unsigned short* __restrict__ o1Wb, const unsigned short* __restrict__ xb,
            const float* __restrict__ headW, const float* __restrict__ hb,
            const float* __restrict__ o0w, const float* __restrict__ o1w,
            const int* __restrict__ tc,
            float* __restrict__ p0, float* __restrict__ p1,
            float* __restrict__ tgh, float* __restrict__ r0, float* __restrict__ r1,
            float* __restrict__ tg0, float* __restrict__ tg1) {
    __shared__ unsigned short smem[4][128 * 64];
    const int tid = threadIdx.x;
    const int lane = tid & 63, wid = tid >> 6;
    const int wr = wid >> 1, wc = wid & 1;
    const int g = lane >> 4, cl = lane & 15;
    int bid = blockIdx.x;

    if (bid < 1008) {
        // ================= out0: 2048 x 8064, K=256, fused exp2-sum =================
        const int row0 = (bid & 15) * 128;
        const int col0 = (bid >> 4) * 128;
        const int sr = wid * 8 + (lane >> 3);
        const int swz = ((lane & 7) ^ (lane >> 3)) * 8;
        const unsigned short* Ab = h01 + (size_t)(row0 + sr) * 320 + swz;
        const unsigned short* Bb = o0Wb + (size_t)(col0 + sr) * 256 + swz;
        auto stage = [&](int buf, int kt) {
            const unsigned short* ga = Ab + kt;
            const unsigned short* gb = Bb + kt;
            unsigned short* la = &smem[buf][wid * 8 * 64];
            unsigned short* lb = &smem[2 + buf][wid * 8 * 64];
#pragma unroll
            for (int i = 0; i < 4; ++i) {
                __builtin_amdgcn_global_load_lds((gas_t)(const void*)(ga + (size_t)i * 32 * 320),
                                                 (las_t)(void*)(la + i * 32 * 64), 16, 0, 0);
                __builtin_amdgcn_global_load_lds((gas_t)(const void*)(gb + (size_t)i * 32 * 256),
                                                 (las_t)(void*)(lb + i * 32 * 64), 16, 0, 0);
            }
        };
        f32x4 acc[4][4] = {};
        stage(0, 0);
        asm volatile("s_waitcnt vmcnt(0)" ::: "memory");
        __builtin_amdgcn_s_barrier();
        const int sA = (cl & 7);
        for (int t = 0; t < 4; ++t) {
            if (t < 3) stage((t + 1) & 1, (t + 1) * 64);
            const unsigned short* Al = &smem[t & 1][(wr * 64 + cl) * 64];
            const unsigned short* Bl = &smem[2 + (t & 1)][(wc * 64 + cl) * 64];
#pragma unroll
            for (int kk2 = 0; kk2 < 2; ++kk2) {
                const int slot = ((kk2 * 4 + g) ^ sA) * 8;
                s16x8 a[4], b[4];
#pragma unroll
                for (int mi = 0; mi < 4; ++mi)
                    a[mi] = *reinterpret_cast<const s16x8*>(Al + mi * 16 * 64 + slot);
#pragma unroll
                for (int ni = 0; ni < 4; ++ni)
                    b[ni] = *reinterpret_cast<const s16x8*>(Bl + ni * 16 * 64 + slot);
#pragma unroll
                for (int mi = 0; mi < 4; ++mi)
#pragma unroll
                    for (int ni = 0; ni < 4; ++ni)
                        acc[mi][ni] = mfma16(a[mi], b[ni], acc[mi][ni]);
            }
            if (t < 3) {
                asm volatile("s_waitcnt vmcnt(0)" ::: "memory");
                __builtin_amdgcn_s_barrier();
            }
        }
        int strip = (bid >> 4) * 2 + wc;
#pragma unroll
        for (int mi = 0; mi < 4; ++mi)
#pragma unroll
            for (int r = 0; r < 4; ++r) {
                float s = 0.f;
#pragma unroll
                for (int ni = 0; ni < 4; ++ni)
                    s += __builtin_amdgcn_exp2f(acc[mi][ni][r]);
                s += __shfl_xor(s, 1, 64);
                s += __shfl_xor(s, 2, 64);
                s += __shfl_xor(s, 4, 64);
                s += __shfl_xor(s, 8, 64);
                if (cl == 0)
                    p0[(size_t)strip * NROWS + row0 + wr * 64 + mi * 16 + g * 4 + r] = s;
            }
        return;
    }
    if (bid < 2016) {
        // ================= out1: 2048 x 40320, K=64, 5 col-tiles/block =================
        bid -= 1008;
        const int row0 = (bid & 15) * 128 + wr * 64;
        const int yb = bid >> 4;
        const int t0 = yb * OUT1_IT;
        s16x8 a[4][2];
#pragma unroll
        for (int mi = 0; mi < 4; ++mi)
#pragma unroll
            for (int kk = 0; kk < 2; ++kk)
                a[mi][kk] = *reinterpret_cast<const s16x8*>(
                    h01 + (size_t)(row0 + mi * 16 + cl) * 320 + 256 + kk * 32 + g * 8);
        const int sr = wid * 8 + (lane >> 3);
        const int swz = ((lane & 7) ^ (lane >> 3)) * 8;
        auto stage = [&](int buf, int tile) {
            const unsigned short* gb = o1Wb + ((size_t)tile * 128 + sr) * 64 + swz;
            unsigned short* lb = &smem[buf][wid * 8 * 64];
#pragma unroll
            for (int i = 0; i < 4; ++i)
                __builtin_amdgcn_global_load_lds((gas_t)(const void*)(gb + (size_t)i * 32 * 64),
                                                 (las_t)(void*)(lb + i * 32 * 64), 16, 0, 0);
        };
        float sexp[4][4] = {};
        const f32x4 z4 = {0.f, 0.f, 0.f, 0.f};
        stage(0, t0);
        asm volatile("s_waitcnt vmcnt(0)" ::: "memory");
        __builtin_amdgcn_s_barrier();
        int buf = 0;
        const int sA = (cl & 7);
#pragma unroll 1
        for (int it = 0; it < OUT1_IT; ++it) {
            if (it + 1 < OUT1_IT) stage(buf ^ 1, t0 + it + 1);
            const unsigned short* Bl = smem[buf];
#pragma unroll
            for (int ni = 0; ni < 4; ++ni) {
                const unsigned short* br = Bl + (wc * 64 + ni * 16 + cl) * 64;
                s16x8 b0 = *reinterpret_cast<const s16x8*>(br + (g ^ sA) * 8);
                s16x8 b1 = *reinterpret_cast<const s16x8*>(br + ((4 + g) ^ sA) * 8);
                f32x4 acc[4];
#pragma unroll
                for (int mi = 0; mi < 4; ++mi)
                    acc[mi] = mfma16(a[mi][0], b0, z4);
#pragma unroll
                for (int mi = 0; mi < 4; ++mi)
                    acc[mi] = mfma16(a[mi][1], b1, acc[mi]);
#pragma unroll
                for (int mi = 0; mi < 4; ++mi)
#pragma unroll
                    for (int r = 0; r < 4; ++r)
                        sexp[mi][r] += __builtin_amdgcn_exp2f(acc[mi][r]);
            }
            if (it + 1 < OUT1_IT) {
                asm volatile("s_waitcnt vmcnt(0)" ::: "memory");
                __builtin_amdgcn_s_barrier();
                buf ^= 1;
            }
        }
#pragma unroll
        for (int mi = 0; mi < 4; ++mi)
#pragma unroll
            for (int r = 0; r < 4; ++r) {
                float s = sexp[mi][r];
                s += __shfl_xor(s, 1, 64);
                s += __shfl_xor(s, 2, 64);
                s += __shfl_xor(s, 4, 64);
                s += __shfl_xor(s, 8, 64);
                if (cl == 0)
                    p1[(size_t)(yb * 2 + wc) * NROWS + row0 + mi * 16 + g * 4 + r] = s;
            }
        return;
    }
    // ================= dots: per-row target / routing logits =================
    bid -= 2016;
    int n = (bid * 256 + tid) >> 6;
    int tch = tc[n], tc0 = tc[2048 + n], tc1 = tc[4096 + n];
    const unsigned short* xr = xb + (size_t)n * 1024 + lane * 16;
    s16x8 x0 = *reinterpret_cast<const s16x8*>(xr);
    s16x8 x1 = *reinterpret_cast<const s16x8*>(xr + 8);
    const float* wh = headW + (size_t)tch * 1024 + lane * 16;
    const float* wa = headW + (size_t)2000 * 1024 + lane * 16;
    const float* wb = headW + (size_t)2001 * 1024 + lane * 16;
    float dh = 0.f, da = 0.f, db = 0.f;
#pragma unroll
    for (int i = 0; i < 8; ++i) {
        float xv = bf2f((unsigned short)x0[i]);
        dh += xv * wh[i]; da += xv * wa[i]; db += xv * wb[i];
    }
#pragma unroll
    for (int i = 0; i < 8; ++i) {
        float xv = bf2f((unsigned short)x1[i]);
        dh += xv * wh[8 + i]; da += xv * wa[8 + i]; db += xv * wb[8 + i];
    }
    ushort4 h0v = *reinterpret_cast<const ushort4*>(h01 + (size_t)n * 320 + lane * 4);
    float4 w0v = *reinterpret_cast<const float4*>(o0w + (size_t)tc0 * 256 + lane * 4);
    float d2 = bf2f(h0v.x) * w0v.x + bf2f(h0v.y) * w0v.y +
               bf2f(h0v.z) * w0v.z + bf2f(h0v.w) * w0v.w;
    float d3 = bf2f(h01[(size_t)n * 320 + 256 + lane]) * o1w[(size_t)tc1 * 64 + lane];
#pragma unroll
    for (int m = 1; m < 64; m <<= 1) {
        dh += __shfl_xor(dh, m, 64);
        da += __shfl_xor(da, m, 64);
        db += __shfl_xor(db, m, 64);
        d2 += __shfl_xor(d2, m, 64);
        d3 += __shfl_xor(d3, m, 64);
    }
    if (lane == 0) {
        tgh[n] = dh + hb[tch];
        r0[n] = da + hb[2000];
        r1[n] = db + hb[2001];
        tg0[n] = d2;
        tg1[n] = d3;
    }
}

// ---------------- finalize ----------------
__global__ void k_finalize(const float* __restrict__ ph, const float* __restrict__ p0,
                           const float* __restrict__ p1, const float* __restrict__ tgh,
                           const float* __restrict__ r0, const float* __restrict__ r1,
                           const float* __restrict__ tg0, const float* __restrict__ tg1,
                           const int* __restrict__ tgt, float* __restrict__ outv,
                           float* __restrict__ bsum) {
    int n = blockIdx.x * 128 + threadIdx.x;   // 16 blocks x 128
    float sh = 0.f, s0 = 0.f, s1 = 0.f;
    for (int s = 0; s < 32; ++s) sh += ph[(size_t)s * NROWS + n];
    for (int s = 0; s < 126; ++s) s0 += p0[(size_t)s * NROWS + n];
    for (int s = 0; s < 126; ++s) s1 += p1[(size_t)s * NROWS + n];
    s0 -= 64.f;   // zero-weight pad cols contribute exp2(0)=1 each
    s1 -= 63.f;
    float lh = __logf(sh), l0 = __logf(s0), l1 = __logf(s1);
    int t = tgt[n];
    float o;
    if (t < 2000) o = tgh[n] - lh;
    else if (t < 10000) o = (r0[n] - lh) + (tg0[n] - l0);
    else o = (r1[n] - lh) + (tg1[n] - l1);
    outv[n] = o;
    __shared__ float red[128];
    red[threadIdx.x] = o;
    __syncthreads();
    for (int s = 64; s > 0; s >>= 1) {
        if (threadIdx.x < s) red[threadIdx.x] += red[threadIdx.x + s];
        __syncthreads();
    }
    if (threadIdx.x == 0) bsum[blockIdx.x] = red[0];
}

__global__ void k_loss(const float* __restrict__ bsum, float* __restrict__ loss) {
    float s = 0.f;
    for (int i = 0; i < 16; ++i) s += bsum[i];
    *loss = -s / (float)NROWS;
}

extern "C" void kernel_launch(void* const* d_in, const int* in_sizes, int n_in,
                              void* d_out, int out_size, void* d_ws, size_t ws_size,
                              hipStream_t stream) {
    const int* targets   = (const int*)d_in[0];
    const float* lhs     = (const float*)d_in[1];
    const int* idx       = (const int*)d_in[3];
    const float* head_W  = (const float*)d_in[4];
    const float* head_b  = (const float*)d_in[5];
    const float* proj0_W = (const float*)d_in[6];
    const float* out0_W  = (const float*)d_in[7];
    const float* proj1_W = (const float*)d_in[8];
    const float* out1_W  = (const float*)d_in[9];

    char* ws = (char*)d_ws;
    size_t off = 0;
    auto alloc = [&](size_t bytes) -> void* {
        void* p = ws + off;
        off += (bytes + 255) & ~(size_t)255;
        return p;
    };

    unsigned short* xb   = (unsigned short*)alloc((size_t)2048 * 1024 * 2);
    unsigned short* wB   = (unsigned short*)alloc((size_t)2432 * 1024 * 2);
    unsigned short* hWb  = wB;
    unsigned short* pW01 = wB + (size_t)2048 * 1024;
    unsigned short* o0Wb = (unsigned short*)alloc((size_t)8064 * 256 * 2);
    unsigned short* o1Wb = (unsigned short*)alloc((size_t)40320 * 64 * 2);
    unsigned short* h01  = (unsigned short*)alloc((size_t)2048 * 320 * 2);
    float* ph  = (float*)alloc((size_t)32 * 2048 * 4);
    float* p0  = (float*)alloc((size_t)126 * 2048 * 4);
    float* p1  = (float*)alloc((size_t)126 * 2048 * 4);
    float* tgh = (float*)alloc(2048 * 4);
    float* r0  = (float*)alloc(2048 * 4);
    float* r1  = (float*)alloc(2048 * 4);
    float* tg0 = (float*)alloc(2048 * 4);
    float* tg1 = (float*)alloc(2048 * 4);
    int*   tc  = (int*)alloc(3 * 2048 * 4);
    float* bias_s = (float*)alloc(2048 * 4);
    float* bsum = (float*)alloc(16 * 4);

    // merged gather + convert + prep
    k_prologue<<<9024, 256, 0, stream>>>(lhs, idx, head_W, proj0_W, proj1_W, out0_W, out1_W,
                                         head_b, targets,
                                         xb, hWb, pW01, o0Wb, o1Wb, bias_s, tc);

    // head (y<16: fused exp2-sum, 32 strips) + proj (y>=16: store h01)
    k_mm<16><<<dim3(16, 19), 256, 0, stream>>>(
        xb, 1024, wB, 1024, bias_s, ph, h01, 320, 320, 16);

    // merged tail: out0 (1008 blocks) | out1 (1008) | dots (512)
    k_tail<<<2528, 256, 0, stream>>>(h01, o0Wb, o1Wb, xb, head_W, head_b, out0_W, out1_W,
                                     tc, p0, p1, tgh, r0, r1, tg0, tg1);

    float* outv = (float*)d_out;
    float* loss = (float*)d_out + NROWS;
    k_finalize<<<16, 128, 0, stream>>>(ph, p0, p1, tgh, r0, r1, tg0, tg1, targets, outv, bsum);
    k_loss<<<1, 1, 0, stream>>>(bsum, loss);
}